// Round 1
// baseline (3489.779 us; speedup 1.0000x reference)
//
#include <hip/hip_runtime.h>
#include <math.h>

#define N_NODES 50000
#define N_EDGES 800000
#define IN_DIM 96
#define NHEADS 8
#define HDIM 12

// ---------------------------------------------------------------------------
// Kernel 1: Q/K/V node projections. Block = 256 threads, 16 nodes per block.
// W staged in LDS (one W at a time, 3 phases), x rows staged in LDS (+4 pad
// so row stride 100 ≡ 4 mod 32 breaks bank aliasing).
// ---------------------------------------------------------------------------
__global__ __launch_bounds__(256) void qkv_kernel(
    const float* __restrict__ x,
    const float* __restrict__ Wq, const float* __restrict__ bq,
    const float* __restrict__ Wk, const float* __restrict__ bk,
    const float* __restrict__ Wv, const float* __restrict__ bv,
    float* __restrict__ Q, float* __restrict__ K, float* __restrict__ V)
{
    __shared__ float xs[16][100];
    __shared__ float Ws[96 * 96];

    const int t = threadIdx.x;
    const int nbase = blockIdx.x * 16;

    // stage 16 x-rows (16*24 float4)
    for (int j = t; j < 16 * 24; j += 256) {
        const int r = j / 24, c4 = j % 24;
        const int n = nbase + r;
        float4 val = make_float4(0.f, 0.f, 0.f, 0.f);
        if (n < N_NODES) val = *(const float4*)&x[(size_t)n * 96 + c4 * 4];
        *(float4*)&xs[r][c4 * 4] = val;
    }

    const int tn = t & 15;   // node within block
    const int tc = t >> 4;   // 0..15 -> cols tc*6 .. tc*6+5
    const int n = nbase + tn;

    const float* Wlist[3] = {Wq, Wk, Wv};
    const float* blist[3] = {bq, bk, bv};
    float* Olist[3] = {Q, K, V};

    for (int w = 0; w < 3; ++w) {
        __syncthreads();  // prev phase compute done (and x staged, first iter)
        const float4* Wg = (const float4*)Wlist[w];
        for (int j = t; j < 2304; j += 256) ((float4*)Ws)[j] = Wg[j];
        __syncthreads();

        float acc[6];
        #pragma unroll
        for (int d = 0; d < 6; ++d) acc[d] = blist[w][tc * 6 + d];

        for (int i = 0; i < 96; ++i) {
            const float xv = xs[tn][i];
            #pragma unroll
            for (int d = 0; d < 6; ++d) acc[d] += xv * Ws[i * 96 + tc * 6 + d];
        }
        if (n < N_NODES) {
            #pragma unroll
            for (int d = 0; d < 6; ++d)
                Olist[w][(size_t)n * 96 + tc * 6 + d] = acc[d];
        }
    }
}

// ---------------------------------------------------------------------------
// Kernel 2: fused edge kernel. Block = 256 threads = 32 edges x 8 heads.
//  - We (96x96) staged in LDS once per block.
//  - edge_attr rows staged in LDS, row stride 100 (pad +4: 8 edges/wave land
//    in distinct banks, 96%32==0 would be 8-way conflict).
//  - per (edge,head) thread: project 12 cols of E, gather K[src]/Q[dst]/V[src]
//    head slice (3x float4, aligned since h*12*4 bytes % 16 == 0), score, exp,
//    atomic scatter into wV (=d_out) and Z.
// ---------------------------------------------------------------------------
__global__ __launch_bounds__(256) void edge_kernel(
    const float* __restrict__ ea,
    const int* __restrict__ ei,          // [2, E] int32
    const float* __restrict__ We, const float* __restrict__ be,
    const float* __restrict__ Q, const float* __restrict__ K,
    const float* __restrict__ V,
    float* __restrict__ wV,              // d_out, [N,96], pre-zeroed
    float* __restrict__ Z)               // [N,8], pre-zeroed
{
    __shared__ float Ws[96 * 96];
    __shared__ float es[32][100];
    __shared__ float bes[96];

    const int t = threadIdx.x;
    const long ebase = (long)blockIdx.x * 32;

    for (int j = t; j < 2304; j += 256) ((float4*)Ws)[j] = ((const float4*)We)[j];
    if (t < 96) bes[t] = be[t];

    for (int j = t; j < 32 * 24; j += 256) {
        const int r = j / 24, c4 = j % 24;
        const long e = ebase + r;
        float4 val = make_float4(0.f, 0.f, 0.f, 0.f);
        if (e < N_EDGES) val = *(const float4*)&ea[e * 96 + c4 * 4];
        *(float4*)&es[r][c4 * 4] = val;
    }
    __syncthreads();

    const int eloc = t >> 3;  // 0..31
    const int h = t & 7;      // head
    const long e = ebase + eloc;
    if (e >= N_EDGES) return;

    // E-projection for this head's 12 columns
    float ep[12];
    #pragma unroll
    for (int d = 0; d < 12; ++d) ep[d] = bes[h * 12 + d];
    for (int i = 0; i < 96; ++i) {
        const float ev = es[eloc][i];
        #pragma unroll
        for (int d = 0; d < 12; ++d) ep[d] += ev * Ws[i * 96 + h * 12 + d];
    }

    const int src = ei[e];
    const int dst = ei[N_EDGES + e];

    float kk[12], qq[12], vv[12];
    {
        const float4* Kp = (const float4*)&K[(size_t)src * 96 + h * 12];
        const float4* Qp = (const float4*)&Q[(size_t)dst * 96 + h * 12];
        const float4* Vp = (const float4*)&V[(size_t)src * 96 + h * 12];
        *(float4*)&kk[0] = Kp[0]; *(float4*)&kk[4] = Kp[1]; *(float4*)&kk[8] = Kp[2];
        *(float4*)&qq[0] = Qp[0]; *(float4*)&qq[4] = Qp[1]; *(float4*)&qq[8] = Qp[2];
        *(float4*)&vv[0] = Vp[0]; *(float4*)&vv[4] = Vp[1]; *(float4*)&vv[8] = Vp[2];
    }

    const float inv_sqrt_d = 0.2886751345948129f;  // 1/sqrt(12)
    float s = 0.f;
    #pragma unroll
    for (int d = 0; d < 12; ++d) s += kk[d] * qq[d] * inv_sqrt_d * ep[d];
    s = fminf(fmaxf(s, -5.f), 5.f);
    s = expf(s);

    float* outp = &wV[(size_t)dst * 96 + h * 12];
    #pragma unroll
    for (int d = 0; d < 12; ++d) atomicAdd(&outp[d], vv[d] * s);
    atomicAdd(&Z[(size_t)dst * 8 + h], s);
}

// ---------------------------------------------------------------------------
// Kernel 3: out /= (Z + 1e-6)
// ---------------------------------------------------------------------------
__global__ __launch_bounds__(256) void div_kernel(
    float* __restrict__ out, const float* __restrict__ Z)
{
    const int i = blockIdx.x * 256 + threadIdx.x;
    if (i < N_NODES * 96) {
        const int n = i / 96;
        const int h = (i % 96) / 12;
        out[i] = out[i] / (Z[n * 8 + h] + 1e-6f);
    }
}

// ---------------------------------------------------------------------------
extern "C" void kernel_launch(void* const* d_in, const int* in_sizes, int n_in,
                              void* d_out, int out_size, void* d_ws, size_t ws_size,
                              hipStream_t stream) {
    const float* x        = (const float*)d_in[0];
    const int*   ei       = (const int*)d_in[1];   // [2, E] (int32: JAX x64 disabled)
    const float* ea       = (const float*)d_in[2];
    const float* Wq       = (const float*)d_in[3];
    const float* bq       = (const float*)d_in[4];
    const float* Wk       = (const float*)d_in[5];
    const float* bk       = (const float*)d_in[6];
    const float* We       = (const float*)d_in[7];
    const float* be       = (const float*)d_in[8];
    const float* Wv       = (const float*)d_in[9];
    const float* bv       = (const float*)d_in[10];

    float* out = (float*)d_out;

    // workspace layout: Q | K | V | Z
    const size_t nqkv = (size_t)N_NODES * 96;
    float* Q = (float*)d_ws;
    float* K = Q + nqkv;
    float* V = K + nqkv;
    float* Z = V + nqkv;

    hipMemsetAsync(d_out, 0, nqkv * sizeof(float), stream);
    hipMemsetAsync(Z, 0, (size_t)N_NODES * NHEADS * sizeof(float), stream);

    {
        dim3 grid((N_NODES + 15) / 16);
        qkv_kernel<<<grid, 256, 0, stream>>>(x, Wq, bq, Wk, bk, Wv, bv, Q, K, V);
    }
    {
        dim3 grid((N_EDGES + 31) / 32);
        edge_kernel<<<grid, 256, 0, stream>>>(ea, ei, We, be, Q, K, V, out, Z);
    }
    {
        dim3 grid((N_NODES * 96 + 255) / 256);
        div_kernel<<<grid, 256, 0, stream>>>(out, Z);
    }
}

// Round 2
// 751.418 us; speedup vs baseline: 4.6443x; 4.6443x over previous
//
#include <hip/hip_runtime.h>
#include <math.h>

#define N_NODES 50000
#define N_EDGES 800000
#define IN_DIM 96
#define NHEADS 8
#define HDIM 12

// ---------------------------------------------------------------------------
// Kernel 1: Q/K/V node projections. Block = 256 threads, 16 nodes per block.
// (unchanged from round 1 — measure before optimizing; edge side dominated)
// ---------------------------------------------------------------------------
__global__ __launch_bounds__(256) void qkv_kernel(
    const float* __restrict__ x,
    const float* __restrict__ Wq, const float* __restrict__ bq,
    const float* __restrict__ Wk, const float* __restrict__ bk,
    const float* __restrict__ Wv, const float* __restrict__ bv,
    float* __restrict__ Q, float* __restrict__ K, float* __restrict__ V)
{
    __shared__ float xs[16][100];
    __shared__ float Ws[96 * 96];

    const int t = threadIdx.x;
    const int nbase = blockIdx.x * 16;

    for (int j = t; j < 16 * 24; j += 256) {
        const int r = j / 24, c4 = j % 24;
        const int n = nbase + r;
        float4 val = make_float4(0.f, 0.f, 0.f, 0.f);
        if (n < N_NODES) val = *(const float4*)&x[(size_t)n * 96 + c4 * 4];
        *(float4*)&xs[r][c4 * 4] = val;
    }

    const int tn = t & 15;
    const int tc = t >> 4;
    const int n = nbase + tn;

    const float* Wlist[3] = {Wq, Wk, Wv};
    const float* blist[3] = {bq, bk, bv};
    float* Olist[3] = {Q, K, V};

    for (int w = 0; w < 3; ++w) {
        __syncthreads();
        const float4* Wg = (const float4*)Wlist[w];
        for (int j = t; j < 2304; j += 256) ((float4*)Ws)[j] = Wg[j];
        __syncthreads();

        float acc[6];
        #pragma unroll
        for (int d = 0; d < 6; ++d) acc[d] = blist[w][tc * 6 + d];

        for (int i = 0; i < 96; ++i) {
            const float xv = xs[tn][i];
            #pragma unroll
            for (int d = 0; d < 6; ++d) acc[d] += xv * Ws[i * 96 + tc * 6 + d];
        }
        if (n < N_NODES) {
            #pragma unroll
            for (int d = 0; d < 6; ++d)
                Olist[w][(size_t)n * 96 + tc * 6 + d] = acc[d];
        }
    }
}

// ---------------------------------------------------------------------------
// CSR build: histogram -> single-block scan -> scatter (src, eid) by dst.
// ---------------------------------------------------------------------------
__global__ __launch_bounds__(256) void hist_kernel(
    const int* __restrict__ ei, int* __restrict__ cursor)
{
    const int e = blockIdx.x * 256 + threadIdx.x;
    if (e < N_EDGES) atomicAdd(&cursor[ei[N_EDGES + e]], 1);
}

__global__ __launch_bounds__(1024) void scan_kernel(
    int* __restrict__ cursor, int* __restrict__ offsets)
{
    __shared__ int tsum[1024];
    const int t = threadIdx.x;
    const int CH = (N_NODES + 1023) / 1024;  // 49
    const int base = t * CH;

    int s = 0;
    for (int i = 0; i < CH; ++i) {
        const int idx = base + i;
        if (idx < N_NODES) s += cursor[idx];
    }
    tsum[t] = s;
    __syncthreads();
    for (int off = 1; off < 1024; off <<= 1) {
        const int v = (t >= off) ? tsum[t - off] : 0;
        __syncthreads();
        tsum[t] += v;
        __syncthreads();
    }
    int run = (t == 0) ? 0 : tsum[t - 1];
    for (int i = 0; i < CH; ++i) {
        const int idx = base + i;
        if (idx < N_NODES) {
            const int c = cursor[idx];
            cursor[idx] = run;       // start offset (scatter cursor)
            offsets[idx] = run;      // CSR offsets for gather
            run += c;
        }
    }
    if (t == 1023) offsets[N_NODES] = run;  // == N_EDGES
}

__global__ __launch_bounds__(256) void scatter_kernel(
    const int* __restrict__ ei, int* __restrict__ cursor,
    int2* __restrict__ sorted)
{
    const int e = blockIdx.x * 256 + threadIdx.x;
    if (e < N_EDGES) {
        const int src = ei[e];
        const int dst = ei[N_EDGES + e];
        const int pos = atomicAdd(&cursor[dst], 1);
        sorted[pos] = make_int2(src, e);
    }
}

// ---------------------------------------------------------------------------
// Score kernel: per (edge,head) compute ep = ea@We + be (head's 12 cols),
// score = exp(clip(sum_d K[src]*Q[dst]*ep/sqrt(12))). Writes score[E,8].
// 64 edges/block, 2 edges per thread (each Ws LDS read feeds 24 FMAs).
// ---------------------------------------------------------------------------
__global__ __launch_bounds__(256) void score_kernel(
    const float* __restrict__ ea,
    const int* __restrict__ ei,
    const float* __restrict__ We, const float* __restrict__ be,
    const float* __restrict__ Q, const float* __restrict__ K,
    float* __restrict__ score)
{
    __shared__ float Ws[96 * 96];     // 36.9 KB
    __shared__ float es[64][100];     // 25.6 KB (pad +4)
    __shared__ float bes[96];

    const int t = threadIdx.x;
    const long ebase = (long)blockIdx.x * 64;

    for (int j = t; j < 2304; j += 256) ((float4*)Ws)[j] = ((const float4*)We)[j];
    if (t < 96) bes[t] = be[t];

    for (int j = t; j < 64 * 24; j += 256) {
        const int r = j / 24, c4 = j % 24;
        const long e = ebase + r;
        float4 v = make_float4(0.f, 0.f, 0.f, 0.f);
        if (e < N_EDGES) v = *(const float4*)&ea[e * 96 + c4 * 4];
        *(float4*)&es[r][c4 * 4] = v;
    }
    __syncthreads();

    const int h = t & 7;
    const int eg = t >> 3;          // 0..31
    const int el0 = eg * 2, el1 = eg * 2 + 1;
    const long e0 = ebase + el0, e1 = ebase + el1;

    float a0[12], a1[12];
    #pragma unroll
    for (int d = 0; d < 12; ++d) { a0[d] = bes[h * 12 + d]; a1[d] = a0[d]; }

    for (int i = 0; i < 96; ++i) {
        float w[12];
        *(float4*)&w[0] = *(const float4*)&Ws[i * 96 + h * 12];
        *(float4*)&w[4] = *(const float4*)&Ws[i * 96 + h * 12 + 4];
        *(float4*)&w[8] = *(const float4*)&Ws[i * 96 + h * 12 + 8];
        const float x0 = es[el0][i];
        const float x1 = es[el1][i];
        #pragma unroll
        for (int d = 0; d < 12; ++d) {
            a0[d] += x0 * w[d];
            a1[d] += x1 * w[d];
        }
    }

    const float inv_sqrt_d = 0.2886751345948129f;  // 1/sqrt(12)

    #pragma unroll 2
    for (int pair = 0; pair < 2; ++pair) {
        const long e = pair ? e1 : e0;
        if (e >= N_EDGES) continue;
        const float* ap = pair ? a1 : a0;
        const int src = ei[e];
        const int dst = ei[N_EDGES + e];
        float kk[12], qq[12];
        {
            const float4* Kp = (const float4*)&K[(size_t)src * 96 + h * 12];
            const float4* Qp = (const float4*)&Q[(size_t)dst * 96 + h * 12];
            *(float4*)&kk[0] = Kp[0]; *(float4*)&kk[4] = Kp[1]; *(float4*)&kk[8] = Kp[2];
            *(float4*)&qq[0] = Qp[0]; *(float4*)&qq[4] = Qp[1]; *(float4*)&qq[8] = Qp[2];
        }
        float s = 0.f;
        #pragma unroll
        for (int d = 0; d < 12; ++d) s += kk[d] * qq[d] * inv_sqrt_d * ap[d];
        s = fminf(fmaxf(s, -5.f), 5.f);
        score[e * 8 + h] = expf(s);
    }
}

// ---------------------------------------------------------------------------
// Gather kernel: thread = (node, col). Walk CSR segment, accumulate
// score * V[src,col] and Z in registers; single clean write of the output.
// ---------------------------------------------------------------------------
__global__ __launch_bounds__(256) void gather_kernel(
    const int* __restrict__ offsets, const int2* __restrict__ sorted,
    const float* __restrict__ score, const float* __restrict__ V,
    float* __restrict__ out)
{
    const int gid = blockIdx.x * 256 + threadIdx.x;
    if (gid >= N_NODES * 96) return;
    const int n = gid / 96;
    const int c = gid % 96;
    const int h = c / 12;

    const int s0 = offsets[n];
    const int s1 = offsets[n + 1];

    float acc = 0.f, z = 0.f;
    for (int p = s0; p < s1; ++p) {
        const int2 se = sorted[p];
        const float sc = score[(size_t)se.y * 8 + h];
        acc += sc * V[(size_t)se.x * 96 + c];
        z += sc;
    }
    out[gid] = acc / (z + 1e-6f);
}

// ---------------------------------------------------------------------------
extern "C" void kernel_launch(void* const* d_in, const int* in_sizes, int n_in,
                              void* d_out, int out_size, void* d_ws, size_t ws_size,
                              hipStream_t stream) {
    const float* x  = (const float*)d_in[0];
    const int*   ei = (const int*)d_in[1];   // [2, E] int32 (JAX x64 disabled)
    const float* ea = (const float*)d_in[2];
    const float* Wq = (const float*)d_in[3];
    const float* bq = (const float*)d_in[4];
    const float* Wk = (const float*)d_in[5];
    const float* bk = (const float*)d_in[6];
    const float* We = (const float*)d_in[7];
    const float* be = (const float*)d_in[8];
    const float* Wv = (const float*)d_in[9];
    const float* bv = (const float*)d_in[10];

    float* out = (float*)d_out;

    // workspace layout: Q | K | V | score | offsets | cursor | pad | sorted
    const size_t nqkv = (size_t)N_NODES * 96;         // 4.8M floats
    float* Q     = (float*)d_ws;
    float* K     = Q + nqkv;
    float* V     = K + nqkv;
    float* score = V + nqkv;                          // [E,8]
    int*   offsets = (int*)(score + (size_t)N_EDGES * 8);   // [N+1]
    int*   cursor  = offsets + (N_NODES + 1);               // [N]
    size_t elems = 3 * nqkv + (size_t)N_EDGES * 8 + (N_NODES + 1) + N_NODES;
    elems += (elems & 1);                                   // 8B-align
    int2*  sorted  = (int2*)((int*)d_ws + elems);           // [E]

    hipMemsetAsync(cursor, 0, N_NODES * sizeof(int), stream);

    qkv_kernel<<<dim3((N_NODES + 15) / 16), 256, 0, stream>>>(
        x, Wq, bq, Wk, bk, Wv, bv, Q, K, V);

    hist_kernel<<<dim3((N_EDGES + 255) / 256), 256, 0, stream>>>(ei, cursor);
    scan_kernel<<<dim3(1), 1024, 0, stream>>>(cursor, offsets);
    scatter_kernel<<<dim3((N_EDGES + 255) / 256), 256, 0, stream>>>(ei, cursor, sorted);

    score_kernel<<<dim3((N_EDGES + 63) / 64), 256, 0, stream>>>(
        ea, ei, We, be, Q, K, score);

    gather_kernel<<<dim3((N_NODES * 96 + 255) / 256), 256, 0, stream>>>(
        offsets, sorted, score, V, out);
}

// Round 3
// 635.711 us; speedup vs baseline: 5.4896x; 1.1820x over previous
//
#include <hip/hip_runtime.h>
#include <math.h>

#define N_NODES 50000
#define N_EDGES 800000
#define IN_DIM 96
#define NHEADS 8
#define HDIM 12

typedef __attribute__((ext_vector_type(8))) short short8;
typedef __attribute__((ext_vector_type(4))) float f32x4;

__device__ __forceinline__ unsigned short f2bf(float f) {
    unsigned int u = __float_as_uint(f);
    return (unsigned short)((u + 0x7FFFu + ((u >> 16) & 1u)) >> 16);
}

// ---------------------------------------------------------------------------
// Kernel 1: Q/K/V node projections (unchanged).
// ---------------------------------------------------------------------------
__global__ __launch_bounds__(256) void qkv_kernel(
    const float* __restrict__ x,
    const float* __restrict__ Wq, const float* __restrict__ bq,
    const float* __restrict__ Wk, const float* __restrict__ bk,
    const float* __restrict__ Wv, const float* __restrict__ bv,
    float* __restrict__ Q, float* __restrict__ K, float* __restrict__ V)
{
    __shared__ float xs[16][100];
    __shared__ float Ws[96 * 96];

    const int t = threadIdx.x;
    const int nbase = blockIdx.x * 16;

    for (int j = t; j < 16 * 24; j += 256) {
        const int r = j / 24, c4 = j % 24;
        const int n = nbase + r;
        float4 val = make_float4(0.f, 0.f, 0.f, 0.f);
        if (n < N_NODES) val = *(const float4*)&x[(size_t)n * 96 + c4 * 4];
        *(float4*)&xs[r][c4 * 4] = val;
    }

    const int tn = t & 15;
    const int tc = t >> 4;
    const int n = nbase + tn;

    const float* Wlist[3] = {Wq, Wk, Wv};
    const float* blist[3] = {bq, bk, bv};
    float* Olist[3] = {Q, K, V};

    for (int w = 0; w < 3; ++w) {
        __syncthreads();
        const float4* Wg = (const float4*)Wlist[w];
        for (int j = t; j < 2304; j += 256) ((float4*)Ws)[j] = Wg[j];
        __syncthreads();

        float acc[6];
        #pragma unroll
        for (int d = 0; d < 6; ++d) acc[d] = blist[w][tc * 6 + d];

        for (int i = 0; i < 96; ++i) {
            const float xv = xs[tn][i];
            #pragma unroll
            for (int d = 0; d < 6; ++d) acc[d] += xv * Ws[i * 96 + tc * 6 + d];
        }
        if (n < N_NODES) {
            #pragma unroll
            for (int d = 0; d < 6; ++d)
                Olist[w][(size_t)n * 96 + tc * 6 + d] = acc[d];
        }
    }
}

// ---------------------------------------------------------------------------
// Setup: We [96(in)][96(out)] fp32 -> WeT [96(out)][96(in)] bf16
// ---------------------------------------------------------------------------
__global__ __launch_bounds__(256) void wet_kernel(
    const float* __restrict__ We, unsigned short* __restrict__ WeT)
{
    const int j = blockIdx.x * 256 + threadIdx.x;
    if (j < 96 * 96) {
        const int k = j / 96, c = j % 96;
        WeT[c * 96 + k] = f2bf(We[j]);
    }
}

// ---------------------------------------------------------------------------
// CSR build: histogram -> single-block scan -> scatter (unchanged).
// ---------------------------------------------------------------------------
__global__ __launch_bounds__(256) void hist_kernel(
    const int* __restrict__ ei, int* __restrict__ cursor)
{
    const int e = blockIdx.x * 256 + threadIdx.x;
    if (e < N_EDGES) atomicAdd(&cursor[ei[N_EDGES + e]], 1);
}

__global__ __launch_bounds__(1024) void scan_kernel(
    int* __restrict__ cursor, int* __restrict__ offsets)
{
    __shared__ int tsum[1024];
    const int t = threadIdx.x;
    const int CH = (N_NODES + 1023) / 1024;  // 49
    const int base = t * CH;

    int s = 0;
    for (int i = 0; i < CH; ++i) {
        const int idx = base + i;
        if (idx < N_NODES) s += cursor[idx];
    }
    tsum[t] = s;
    __syncthreads();
    for (int off = 1; off < 1024; off <<= 1) {
        const int v = (t >= off) ? tsum[t - off] : 0;
        __syncthreads();
        tsum[t] += v;
        __syncthreads();
    }
    int run = (t == 0) ? 0 : tsum[t - 1];
    for (int i = 0; i < CH; ++i) {
        const int idx = base + i;
        if (idx < N_NODES) {
            const int c = cursor[idx];
            cursor[idx] = run;
            offsets[idx] = run;
            run += c;
        }
    }
    if (t == 1023) offsets[N_NODES] = run;
}

__global__ __launch_bounds__(256) void scatter_kernel(
    const int* __restrict__ ei, int* __restrict__ cursor,
    int2* __restrict__ sorted)
{
    const int e = blockIdx.x * 256 + threadIdx.x;
    if (e < N_EDGES) {
        const int src = ei[e];
        const int dst = ei[N_EDGES + e];
        const int pos = atomicAdd(&cursor[dst], 1);
        sorted[pos] = make_int2(src, e);
    }
}

// ---------------------------------------------------------------------------
// Score kernel (MFMA): per block of 64 edges,
//   E_proj = ea_tile @ We via mfma_f32_16x16x32_bf16 -> ep LDS,
//   then per (edge,head): gather K[src]/Q[dst], dot with ep, exp, write.
// 800000 % 64 == 0: no tail handling needed.
// ---------------------------------------------------------------------------
__global__ __launch_bounds__(256) void score_kernel(
    const float* __restrict__ ea,
    const int* __restrict__ ei,
    const unsigned short* __restrict__ WeT,  // [96 out][96 in] bf16
    const float* __restrict__ be,
    const float* __restrict__ Q, const float* __restrict__ K,
    float* __restrict__ score)
{
    __shared__ unsigned short WsT[96 * 104];  // 19968 B (pad: 208B row stride)
    __shared__ unsigned short es[64 * 104];   // 13312 B
    __shared__ float ep[64 * 100];            // 25600 B (pad: 400B row stride)
    __shared__ float bes[96];

    const int t = threadIdx.x;
    const long ebase = (long)blockIdx.x * 64;

    // stage WeT (bf16), rows padded to 104 elems
    for (int j = t; j < 96 * 12; j += 256) {
        const int c = j / 12, kc = j % 12;
        *(uint4*)&WsT[c * 104 + kc * 8] = *(const uint4*)&WeT[c * 96 + kc * 8];
    }
    if (t < 96) bes[t] = be[t];

    // stage ea tile as bf16
    for (int j = t; j < 64 * 12; j += 256) {
        const int r = j / 12, kc = j % 12;
        const float* src = &ea[(ebase + r) * 96 + kc * 8];
        const float4 f0 = *(const float4*)src;
        const float4 f1 = *(const float4*)(src + 4);
        unsigned short b[8] = {f2bf(f0.x), f2bf(f0.y), f2bf(f0.z), f2bf(f0.w),
                               f2bf(f1.x), f2bf(f1.y), f2bf(f1.z), f2bf(f1.w)};
        *(uint4*)&es[r * 104 + kc * 8] = *(uint4*)b;
    }
    __syncthreads();

    // MFMA: wave wid owns edge-rows 16*wid..16*wid+15, all 96 output cols.
    const int wid = t >> 6;
    const int lid = t & 63;
    const int l15 = lid & 15;
    const int lg  = lid >> 4;

    f32x4 acc[6] = {};
    #pragma unroll
    for (int kk = 0; kk < 3; ++kk) {
        const short8 a = *(const short8*)&es[(wid * 16 + l15) * 104 + kk * 32 + lg * 8];
        #pragma unroll
        for (int ct = 0; ct < 6; ++ct) {
            const short8 b = *(const short8*)&WsT[(ct * 16 + l15) * 104 + kk * 32 + lg * 8];
            acc[ct] = __builtin_amdgcn_mfma_f32_16x16x32_bf16(a, b, acc[ct], 0, 0, 0);
        }
    }
    // C layout: col = lane&15, row = (lane>>4)*4 + reg
    #pragma unroll
    for (int ct = 0; ct < 6; ++ct) {
        const int col = ct * 16 + l15;
        const float bias = bes[col];
        #pragma unroll
        for (int r = 0; r < 4; ++r)
            ep[(wid * 16 + lg * 4 + r) * 100 + col] = acc[ct][r] + bias;
    }
    __syncthreads();

    // score phase: 2 passes x (32 edges x 8 heads)
    const float inv_sqrt_d = 0.2886751345948129f;  // 1/sqrt(12)
    #pragma unroll 2
    for (int pass = 0; pass < 2; ++pass) {
        const int el = pass * 32 + (t >> 3);
        const int h = t & 7;
        const long e = ebase + el;
        const int src = ei[e];
        const int dst = ei[N_EDGES + e];

        float epv[12], kk_[12], qq[12];
        *(float4*)&epv[0] = *(const float4*)&ep[el * 100 + h * 12];
        *(float4*)&epv[4] = *(const float4*)&ep[el * 100 + h * 12 + 4];
        *(float4*)&epv[8] = *(const float4*)&ep[el * 100 + h * 12 + 8];
        {
            const float4* Kp = (const float4*)&K[(size_t)src * 96 + h * 12];
            const float4* Qp = (const float4*)&Q[(size_t)dst * 96 + h * 12];
            *(float4*)&kk_[0] = Kp[0]; *(float4*)&kk_[4] = Kp[1]; *(float4*)&kk_[8] = Kp[2];
            *(float4*)&qq[0] = Qp[0]; *(float4*)&qq[4] = Qp[1]; *(float4*)&qq[8] = Qp[2];
        }
        float s = 0.f;
        #pragma unroll
        for (int d = 0; d < 12; ++d) s += kk_[d] * qq[d] * inv_sqrt_d * epv[d];
        s = fminf(fmaxf(s, -5.f), 5.f);
        score[e * 8 + h] = expf(s);
    }
}

// ---------------------------------------------------------------------------
// Gather kernel (unchanged).
// ---------------------------------------------------------------------------
__global__ __launch_bounds__(256) void gather_kernel(
    const int* __restrict__ offsets, const int2* __restrict__ sorted,
    const float* __restrict__ score, const float* __restrict__ V,
    float* __restrict__ out)
{
    const int gid = blockIdx.x * 256 + threadIdx.x;
    if (gid >= N_NODES * 96) return;
    const int n = gid / 96;
    const int c = gid % 96;
    const int h = c / 12;

    const int s0 = offsets[n];
    const int s1 = offsets[n + 1];

    float acc = 0.f, z = 0.f;
    for (int p = s0; p < s1; ++p) {
        const int2 se = sorted[p];
        const float sc = score[(size_t)se.y * 8 + h];
        acc += sc * V[(size_t)se.x * 96 + c];
        z += sc;
    }
    out[gid] = acc / (z + 1e-6f);
}

// ---------------------------------------------------------------------------
extern "C" void kernel_launch(void* const* d_in, const int* in_sizes, int n_in,
                              void* d_out, int out_size, void* d_ws, size_t ws_size,
                              hipStream_t stream) {
    const float* x  = (const float*)d_in[0];
    const int*   ei = (const int*)d_in[1];   // [2, E] int32 (JAX x64 disabled)
    const float* ea = (const float*)d_in[2];
    const float* Wq = (const float*)d_in[3];
    const float* bq = (const float*)d_in[4];
    const float* Wk = (const float*)d_in[5];
    const float* bk = (const float*)d_in[6];
    const float* We = (const float*)d_in[7];
    const float* be = (const float*)d_in[8];
    const float* Wv = (const float*)d_in[9];
    const float* bv = (const float*)d_in[10];

    float* out = (float*)d_out;

    // workspace: Q | K | V | score | offsets | cursor | pad | sorted | WeT
    const size_t nqkv = (size_t)N_NODES * 96;
    float* Q     = (float*)d_ws;
    float* K     = Q + nqkv;
    float* V     = K + nqkv;
    float* score = V + nqkv;                                // [E,8]
    int*   offsets = (int*)(score + (size_t)N_EDGES * 8);   // [N+1]
    int*   cursor  = offsets + (N_NODES + 1);               // [N]
    size_t elems = 3 * nqkv + (size_t)N_EDGES * 8 + (N_NODES + 1) + N_NODES;
    elems += (elems & 1);
    int2*  sorted  = (int2*)((int*)d_ws + elems);           // [E]
    unsigned short* WeT = (unsigned short*)(sorted + N_EDGES);  // [96*96] bf16

    hipMemsetAsync(cursor, 0, N_NODES * sizeof(int), stream);

    wet_kernel<<<dim3(36), 256, 0, stream>>>(We, WeT);

    qkv_kernel<<<dim3((N_NODES + 15) / 16), 256, 0, stream>>>(
        x, Wq, bq, Wk, bk, Wv, bv, Q, K, V);

    hist_kernel<<<dim3((N_EDGES + 255) / 256), 256, 0, stream>>>(ei, cursor);
    scan_kernel<<<dim3(1), 1024, 0, stream>>>(cursor, offsets);
    scatter_kernel<<<dim3((N_EDGES + 255) / 256), 256, 0, stream>>>(ei, cursor, sorted);

    score_kernel<<<dim3(N_EDGES / 64), 256, 0, stream>>>(
        ea, ei, WeT, be, Q, K, score);

    gather_kernel<<<dim3((N_NODES * 96 + 255) / 256), 256, 0, stream>>>(
        offsets, sorted, score, V, out);
}

// Round 4
// 535.517 us; speedup vs baseline: 6.5167x; 1.1871x over previous
//
#include <hip/hip_runtime.h>
#include <math.h>

#define N_NODES 50000
#define N_EDGES 800000
#define IN_DIM 96
#define NHEADS 8
#define HDIM 12

typedef __attribute__((ext_vector_type(8))) short short8;
typedef __attribute__((ext_vector_type(4))) float f32x4;

__device__ __forceinline__ unsigned short f2bf(float f) {
    unsigned int u = __float_as_uint(f);
    return (unsigned short)((u + 0x7FFFu + ((u >> 16) & 1u)) >> 16);
}

// ---------------------------------------------------------------------------
// Kernel 1: Q/K/V projections, fp32, register-blocked.
// Block = 256 threads, 64 nodes. Thread = 4 nodes x 6 cols (acc[4][6]).
// x staged TRANSPOSED in LDS (xs[dim][node], pad 64->68 so float4 reads are
// 16B-aligned and conflict-free). FMA:LDS-float ratio 2.4:1 (was 0.86:1).
// ---------------------------------------------------------------------------
__global__ __launch_bounds__(256) void qkv_kernel(
    const float* __restrict__ x,
    const float* __restrict__ Wq, const float* __restrict__ bq,
    const float* __restrict__ Wk, const float* __restrict__ bk,
    const float* __restrict__ Wv, const float* __restrict__ bv,
    float* __restrict__ Q, float* __restrict__ K, float* __restrict__ V)
{
    __shared__ float xs[96][68];   // 26112 B, transposed
    __shared__ float Ws[96 * 96];  // 36864 B
    __shared__ float bs[96];

    const int t = threadIdx.x;
    const int nbase = blockIdx.x * 64;

    // stage x transposed: 64 nodes x 24 float4
    for (int j = t; j < 64 * 24; j += 256) {
        const int r = j / 24, c4 = j % 24;
        const int n = nbase + r;
        float4 val = make_float4(0.f, 0.f, 0.f, 0.f);
        if (n < N_NODES) val = *(const float4*)&x[(size_t)n * 96 + c4 * 4];
        xs[c4 * 4 + 0][r] = val.x;
        xs[c4 * 4 + 1][r] = val.y;
        xs[c4 * 4 + 2][r] = val.z;
        xs[c4 * 4 + 3][r] = val.w;
    }

    const int np = t & 15;   // node-group: nodes np*4 .. np*4+3
    const int tc = t >> 4;   // col-group: cols tc*6 .. tc*6+5

    const float* Wlist[3] = {Wq, Wk, Wv};
    const float* blist[3] = {bq, bk, bv};
    float* Olist[3] = {Q, K, V};

    for (int w = 0; w < 3; ++w) {
        __syncthreads();
        const float4* Wg = (const float4*)Wlist[w];
        for (int j = t; j < 2304; j += 256) ((float4*)Ws)[j] = Wg[j];
        if (t < 96) bs[t] = blist[w][t];
        __syncthreads();

        float acc0[6], acc1[6], acc2[6], acc3[6];
        #pragma unroll
        for (int d = 0; d < 6; ++d) {
            const float b = bs[tc * 6 + d];
            acc0[d] = b; acc1[d] = b; acc2[d] = b; acc3[d] = b;
        }

        for (int i = 0; i < 96; ++i) {
            const float4 xv = *(const float4*)&xs[i][np * 4];
            const float2 wa = *(const float2*)&Ws[i * 96 + tc * 6];
            const float2 wb = *(const float2*)&Ws[i * 96 + tc * 6 + 2];
            const float2 wc = *(const float2*)&Ws[i * 96 + tc * 6 + 4];
            const float wv[6] = {wa.x, wa.y, wb.x, wb.y, wc.x, wc.y};
            #pragma unroll
            for (int d = 0; d < 6; ++d) {
                acc0[d] += xv.x * wv[d];
                acc1[d] += xv.y * wv[d];
                acc2[d] += xv.z * wv[d];
                acc3[d] += xv.w * wv[d];
            }
        }

        float* Op = Olist[w];
        #pragma unroll
        for (int r = 0; r < 4; ++r) {
            const int n = nbase + np * 4 + r;
            if (n < N_NODES) {
                const float* ap = (r == 0) ? acc0 : (r == 1) ? acc1 : (r == 2) ? acc2 : acc3;
                float* dst = &Op[(size_t)n * 96 + tc * 6];
                *(float2*)&dst[0] = make_float2(ap[0], ap[1]);
                *(float2*)&dst[2] = make_float2(ap[2], ap[3]);
                *(float2*)&dst[4] = make_float2(ap[4], ap[5]);
            }
        }
    }
}

// ---------------------------------------------------------------------------
// Setup: We [96(in)][96(out)] fp32 -> WeT [96(out)][96(in)] bf16
// ---------------------------------------------------------------------------
__global__ __launch_bounds__(256) void wet_kernel(
    const float* __restrict__ We, unsigned short* __restrict__ WeT)
{
    const int j = blockIdx.x * 256 + threadIdx.x;
    if (j < 96 * 96) {
        const int k = j / 96, c = j % 96;
        WeT[c * 96 + k] = f2bf(We[j]);
    }
}

// ---------------------------------------------------------------------------
// CSR build: histogram -> single-block scan -> scatter.
// scatter now emits src-only CSR payload + epos map (edge -> CSR slot) so
// scores can be written directly in CSR order.
// ---------------------------------------------------------------------------
__global__ __launch_bounds__(256) void hist_kernel(
    const int* __restrict__ ei, int* __restrict__ cursor)
{
    const int e = blockIdx.x * 256 + threadIdx.x;
    if (e < N_EDGES) atomicAdd(&cursor[ei[N_EDGES + e]], 1);
}

__global__ __launch_bounds__(1024) void scan_kernel(
    int* __restrict__ cursor, int* __restrict__ offsets)
{
    __shared__ int tsum[1024];
    const int t = threadIdx.x;
    const int CH = (N_NODES + 1023) / 1024;  // 49
    const int base = t * CH;

    int s = 0;
    for (int i = 0; i < CH; ++i) {
        const int idx = base + i;
        if (idx < N_NODES) s += cursor[idx];
    }
    tsum[t] = s;
    __syncthreads();
    for (int off = 1; off < 1024; off <<= 1) {
        const int v = (t >= off) ? tsum[t - off] : 0;
        __syncthreads();
        tsum[t] += v;
        __syncthreads();
    }
    int run = (t == 0) ? 0 : tsum[t - 1];
    for (int i = 0; i < CH; ++i) {
        const int idx = base + i;
        if (idx < N_NODES) {
            const int c = cursor[idx];
            cursor[idx] = run;
            offsets[idx] = run;
            run += c;
        }
    }
    if (t == 1023) offsets[N_NODES] = run;
}

__global__ __launch_bounds__(256) void scatter_kernel(
    const int* __restrict__ ei, int* __restrict__ cursor,
    int* __restrict__ sorted_src, int* __restrict__ epos)
{
    const int e = blockIdx.x * 256 + threadIdx.x;
    if (e < N_EDGES) {
        const int src = ei[e];
        const int dst = ei[N_EDGES + e];
        const int pos = atomicAdd(&cursor[dst], 1);
        sorted_src[pos] = src;
        epos[e] = pos;
    }
}

// ---------------------------------------------------------------------------
// Score kernel (MFMA): E_proj = ea_tile @ We -> ep LDS, then per (edge,head)
// gather K[src]/Q[dst], dot, exp, write score in CSR order via epos.
// ---------------------------------------------------------------------------
__global__ __launch_bounds__(256) void score_kernel(
    const float* __restrict__ ea,
    const int* __restrict__ ei,
    const unsigned short* __restrict__ WeT,  // [96 out][96 in] bf16
    const float* __restrict__ be,
    const float* __restrict__ Q, const float* __restrict__ K,
    const int* __restrict__ epos,
    float* __restrict__ score_s)             // [E,8] in CSR slot order
{
    __shared__ unsigned short WsT[96 * 104];
    __shared__ unsigned short es[64 * 104];
    __shared__ float ep[64 * 100];
    __shared__ float bes[96];

    const int t = threadIdx.x;
    const long ebase = (long)blockIdx.x * 64;

    for (int j = t; j < 96 * 12; j += 256) {
        const int c = j / 12, kc = j % 12;
        *(uint4*)&WsT[c * 104 + kc * 8] = *(const uint4*)&WeT[c * 96 + kc * 8];
    }
    if (t < 96) bes[t] = be[t];

    for (int j = t; j < 64 * 12; j += 256) {
        const int r = j / 12, kc = j % 12;
        const float* src = &ea[(ebase + r) * 96 + kc * 8];
        const float4 f0 = *(const float4*)src;
        const float4 f1 = *(const float4*)(src + 4);
        unsigned short b[8] = {f2bf(f0.x), f2bf(f0.y), f2bf(f0.z), f2bf(f0.w),
                               f2bf(f1.x), f2bf(f1.y), f2bf(f1.z), f2bf(f1.w)};
        *(uint4*)&es[r * 104 + kc * 8] = *(uint4*)b;
    }
    __syncthreads();

    const int wid = t >> 6;
    const int lid = t & 63;
    const int l15 = lid & 15;
    const int lg  = lid >> 4;

    f32x4 acc[6] = {};
    #pragma unroll
    for (int kk = 0; kk < 3; ++kk) {
        const short8 a = *(const short8*)&es[(wid * 16 + l15) * 104 + kk * 32 + lg * 8];
        #pragma unroll
        for (int ct = 0; ct < 6; ++ct) {
            const short8 b = *(const short8*)&WsT[(ct * 16 + l15) * 104 + kk * 32 + lg * 8];
            acc[ct] = __builtin_amdgcn_mfma_f32_16x16x32_bf16(a, b, acc[ct], 0, 0, 0);
        }
    }
    #pragma unroll
    for (int ct = 0; ct < 6; ++ct) {
        const int col = ct * 16 + l15;
        const float bias = bes[col];
        #pragma unroll
        for (int r = 0; r < 4; ++r)
            ep[(wid * 16 + lg * 4 + r) * 100 + col] = acc[ct][r] + bias;
    }
    __syncthreads();

    const float inv_sqrt_d = 0.2886751345948129f;  // 1/sqrt(12)
    #pragma unroll 2
    for (int pass = 0; pass < 2; ++pass) {
        const int el = pass * 32 + (t >> 3);
        const int h = t & 7;
        const long e = ebase + el;
        const int src = ei[e];
        const int dst = ei[N_EDGES + e];
        const int pos = epos[e];

        float epv[12], kk_[12], qq[12];
        *(float4*)&epv[0] = *(const float4*)&ep[el * 100 + h * 12];
        *(float4*)&epv[4] = *(const float4*)&ep[el * 100 + h * 12 + 4];
        *(float4*)&epv[8] = *(const float4*)&ep[el * 100 + h * 12 + 8];
        {
            const float4* Kp = (const float4*)&K[(size_t)src * 96 + h * 12];
            const float4* Qp = (const float4*)&Q[(size_t)dst * 96 + h * 12];
            *(float4*)&kk_[0] = Kp[0]; *(float4*)&kk_[4] = Kp[1]; *(float4*)&kk_[8] = Kp[2];
            *(float4*)&qq[0] = Qp[0]; *(float4*)&qq[4] = Qp[1]; *(float4*)&qq[8] = Qp[2];
        }
        float s = 0.f;
        #pragma unroll
        for (int d = 0; d < 12; ++d) s += kk_[d] * qq[d] * inv_sqrt_d * epv[d];
        s = fminf(fmaxf(s, -5.f), 5.f);
        score_s[(size_t)pos * 8 + h] = expf(s);
    }
}

// ---------------------------------------------------------------------------
// Gather kernel: thread = (node, 4-col group). CSR walk with sequential
// sorted_src / score_s streams, one random float4 V load per edge, unroll-2.
// ---------------------------------------------------------------------------
__global__ __launch_bounds__(256) void gather_kernel(
    const int* __restrict__ offsets, const int* __restrict__ sorted_src,
    const float* __restrict__ score_s, const float* __restrict__ V,
    float* __restrict__ out)
{
    const int gid = blockIdx.x * 256 + threadIdx.x;
    if (gid >= N_NODES * 24) return;
    const int n = gid / 24;
    const int c4 = gid % 24;
    const int h = c4 / 3;           // 4 cols always within one head (12%4==0)

    const int s0 = offsets[n];
    const int s1 = offsets[n + 1];

    float ax = 0.f, ay = 0.f, az = 0.f, aw = 0.f, z = 0.f;
    int p = s0;
    for (; p + 2 <= s1; p += 2) {
        const int srcA = sorted_src[p];
        const int srcB = sorted_src[p + 1];
        const float scA = score_s[(size_t)p * 8 + h];
        const float scB = score_s[(size_t)(p + 1) * 8 + h];
        const float4 vA = *(const float4*)&V[(size_t)srcA * 96 + c4 * 4];
        const float4 vB = *(const float4*)&V[(size_t)srcB * 96 + c4 * 4];
        ax += scA * vA.x + scB * vB.x;
        ay += scA * vA.y + scB * vB.y;
        az += scA * vA.z + scB * vB.z;
        aw += scA * vA.w + scB * vB.w;
        z  += scA + scB;
    }
    if (p < s1) {
        const int srcA = sorted_src[p];
        const float scA = score_s[(size_t)p * 8 + h];
        const float4 vA = *(const float4*)&V[(size_t)srcA * 96 + c4 * 4];
        ax += scA * vA.x; ay += scA * vA.y; az += scA * vA.z; aw += scA * vA.w;
        z  += scA;
    }
    const float inv = 1.f / (z + 1e-6f);
    *(float4*)&out[(size_t)n * 96 + c4 * 4] =
        make_float4(ax * inv, ay * inv, az * inv, aw * inv);
}

// ---------------------------------------------------------------------------
extern "C" void kernel_launch(void* const* d_in, const int* in_sizes, int n_in,
                              void* d_out, int out_size, void* d_ws, size_t ws_size,
                              hipStream_t stream) {
    const float* x  = (const float*)d_in[0];
    const int*   ei = (const int*)d_in[1];   // [2, E] int32 (JAX x64 disabled)
    const float* ea = (const float*)d_in[2];
    const float* Wq = (const float*)d_in[3];
    const float* bq = (const float*)d_in[4];
    const float* Wk = (const float*)d_in[5];
    const float* bk = (const float*)d_in[6];
    const float* We = (const float*)d_in[7];
    const float* be = (const float*)d_in[8];
    const float* Wv = (const float*)d_in[9];
    const float* bv = (const float*)d_in[10];

    float* out = (float*)d_out;

    // workspace: Q | K | V | score_s | offsets | cursor | epos | sorted_src | WeT
    const size_t nqkv = (size_t)N_NODES * 96;
    float* Q       = (float*)d_ws;
    float* K       = Q + nqkv;
    float* V       = K + nqkv;
    float* score_s = V + nqkv;                                // [E,8]
    int* offsets    = (int*)(score_s + (size_t)N_EDGES * 8);  // [N+1]
    int* cursor     = offsets + (N_NODES + 1);                // [N]
    int* epos       = cursor + N_NODES;                       // [E]
    int* sorted_src = epos + N_EDGES;                         // [E]
    unsigned short* WeT = (unsigned short*)(sorted_src + N_EDGES);  // [96*96] bf16

    hipMemsetAsync(cursor, 0, N_NODES * sizeof(int), stream);

    wet_kernel<<<dim3(36), 256, 0, stream>>>(We, WeT);

    qkv_kernel<<<dim3((N_NODES + 63) / 64), 256, 0, stream>>>(
        x, Wq, bq, Wk, bk, Wv, bv, Q, K, V);

    hist_kernel<<<dim3((N_EDGES + 255) / 256), 256, 0, stream>>>(ei, cursor);
    scan_kernel<<<dim3(1), 1024, 0, stream>>>(cursor, offsets);
    scatter_kernel<<<dim3((N_EDGES + 255) / 256), 256, 0, stream>>>(
        ei, cursor, sorted_src, epos);

    score_kernel<<<dim3(N_EDGES / 64), 256, 0, stream>>>(
        ea, ei, WeT, be, Q, K, epos, score_s);

    gather_kernel<<<dim3((N_NODES * 24 + 255) / 256), 256, 0, stream>>>(
        offsets, sorted_src, score_s, V, out);
}

// Round 5
// 485.456 us; speedup vs baseline: 7.1887x; 1.1031x over previous
//
#include <hip/hip_runtime.h>
#include <math.h>

#define N_NODES 50000
#define N_EDGES 800000
#define IN_DIM 96
#define NHEADS 8
#define HDIM 12

typedef __attribute__((ext_vector_type(8))) short short8;
typedef __attribute__((ext_vector_type(4))) float f32x4;

__device__ __forceinline__ unsigned short f2bf(float f) {
    unsigned int u = __float_as_uint(f);
    return (unsigned short)((u + 0x7FFFu + ((u >> 16) & 1u)) >> 16);
}
__device__ __forceinline__ float bf2f_lo(unsigned int u) {
    return __uint_as_float(u << 16);
}
__device__ __forceinline__ float bf2f_hi(unsigned int u) {
    return __uint_as_float(u & 0xFFFF0000u);
}

// ---------------------------------------------------------------------------
// Kernel 1: Q/K/V projections, fp32 math, register-blocked.
// Q,K written fp32; V written bf16 (only gather consumes V -> halves its
// random-read traffic).
// ---------------------------------------------------------------------------
__global__ __launch_bounds__(256) void qkv_kernel(
    const float* __restrict__ x,
    const float* __restrict__ Wq, const float* __restrict__ bq,
    const float* __restrict__ Wk, const float* __restrict__ bk,
    const float* __restrict__ Wv, const float* __restrict__ bv,
    float* __restrict__ Q, float* __restrict__ K,
    unsigned short* __restrict__ Vb)
{
    __shared__ float xs[96][68];   // transposed, pad 64->68
    __shared__ float Ws[96 * 96];
    __shared__ float bs[96];

    const int t = threadIdx.x;
    const int nbase = blockIdx.x * 64;

    for (int j = t; j < 64 * 24; j += 256) {
        const int r = j / 24, c4 = j % 24;
        const int n = nbase + r;
        float4 val = make_float4(0.f, 0.f, 0.f, 0.f);
        if (n < N_NODES) val = *(const float4*)&x[(size_t)n * 96 + c4 * 4];
        xs[c4 * 4 + 0][r] = val.x;
        xs[c4 * 4 + 1][r] = val.y;
        xs[c4 * 4 + 2][r] = val.z;
        xs[c4 * 4 + 3][r] = val.w;
    }

    const int np = t & 15;   // nodes np*4 .. np*4+3
    const int tc = t >> 4;   // cols tc*6 .. tc*6+5

    const float* Wlist[3] = {Wq, Wk, Wv};
    const float* blist[3] = {bq, bk, bv};

    for (int w = 0; w < 3; ++w) {
        __syncthreads();
        const float4* Wg = (const float4*)Wlist[w];
        for (int j = t; j < 2304; j += 256) ((float4*)Ws)[j] = Wg[j];
        if (t < 96) bs[t] = blist[w][t];
        __syncthreads();

        float acc0[6], acc1[6], acc2[6], acc3[6];
        #pragma unroll
        for (int d = 0; d < 6; ++d) {
            const float b = bs[tc * 6 + d];
            acc0[d] = b; acc1[d] = b; acc2[d] = b; acc3[d] = b;
        }

        for (int i = 0; i < 96; ++i) {
            const float4 xv = *(const float4*)&xs[i][np * 4];
            const float2 wa = *(const float2*)&Ws[i * 96 + tc * 6];
            const float2 wb = *(const float2*)&Ws[i * 96 + tc * 6 + 2];
            const float2 wc = *(const float2*)&Ws[i * 96 + tc * 6 + 4];
            const float wv[6] = {wa.x, wa.y, wb.x, wb.y, wc.x, wc.y};
            #pragma unroll
            for (int d = 0; d < 6; ++d) {
                acc0[d] += xv.x * wv[d];
                acc1[d] += xv.y * wv[d];
                acc2[d] += xv.z * wv[d];
                acc3[d] += xv.w * wv[d];
            }
        }

        #pragma unroll
        for (int r = 0; r < 4; ++r) {
            const int n = nbase + np * 4 + r;
            if (n >= N_NODES) continue;
            const float* ap = (r == 0) ? acc0 : (r == 1) ? acc1 : (r == 2) ? acc2 : acc3;
            if (w == 2) {
                unsigned int* dst = (unsigned int*)&Vb[(size_t)n * 96 + tc * 6];
                dst[0] = (unsigned int)f2bf(ap[0]) | ((unsigned int)f2bf(ap[1]) << 16);
                dst[1] = (unsigned int)f2bf(ap[2]) | ((unsigned int)f2bf(ap[3]) << 16);
                dst[2] = (unsigned int)f2bf(ap[4]) | ((unsigned int)f2bf(ap[5]) << 16);
            } else {
                float* dst = (w == 0) ? &Q[(size_t)n * 96 + tc * 6]
                                      : &K[(size_t)n * 96 + tc * 6];
                *(float2*)&dst[0] = make_float2(ap[0], ap[1]);
                *(float2*)&dst[2] = make_float2(ap[2], ap[3]);
                *(float2*)&dst[4] = make_float2(ap[4], ap[5]);
            }
        }
    }
}

// ---------------------------------------------------------------------------
// Setup: We [96(in)][96(out)] fp32 -> WeT [96(out)][96(in)] bf16
// ---------------------------------------------------------------------------
__global__ __launch_bounds__(256) void wet_kernel(
    const float* __restrict__ We, unsigned short* __restrict__ WeT)
{
    const int j = blockIdx.x * 256 + threadIdx.x;
    if (j < 96 * 96) {
        const int k = j / 96, c = j % 96;
        WeT[c * 96 + k] = f2bf(We[j]);
    }
}

// ---------------------------------------------------------------------------
// CSR build: histogram -> single-block scan -> scatter (+ epos map).
// ---------------------------------------------------------------------------
__global__ __launch_bounds__(256) void hist_kernel(
    const int* __restrict__ ei, int* __restrict__ cursor)
{
    const int e = blockIdx.x * 256 + threadIdx.x;
    if (e < N_EDGES) atomicAdd(&cursor[ei[N_EDGES + e]], 1);
}

__global__ __launch_bounds__(1024) void scan_kernel(
    int* __restrict__ cursor, int* __restrict__ offsets)
{
    __shared__ int tsum[1024];
    const int t = threadIdx.x;
    const int CH = (N_NODES + 1023) / 1024;  // 49
    const int base = t * CH;

    int s = 0;
    for (int i = 0; i < CH; ++i) {
        const int idx = base + i;
        if (idx < N_NODES) s += cursor[idx];
    }
    tsum[t] = s;
    __syncthreads();
    for (int off = 1; off < 1024; off <<= 1) {
        const int v = (t >= off) ? tsum[t - off] : 0;
        __syncthreads();
        tsum[t] += v;
        __syncthreads();
    }
    int run = (t == 0) ? 0 : tsum[t - 1];
    for (int i = 0; i < CH; ++i) {
        const int idx = base + i;
        if (idx < N_NODES) {
            const int c = cursor[idx];
            cursor[idx] = run;
            offsets[idx] = run;
            run += c;
        }
    }
    if (t == 1023) offsets[N_NODES] = run;
}

__global__ __launch_bounds__(256) void scatter_kernel(
    const int* __restrict__ ei, int* __restrict__ cursor,
    int* __restrict__ sorted_src, int* __restrict__ epos)
{
    const int e = blockIdx.x * 256 + threadIdx.x;
    if (e < N_EDGES) {
        const int src = ei[e];
        const int dst = ei[N_EDGES + e];
        const int pos = atomicAdd(&cursor[dst], 1);
        sorted_src[pos] = src;
        epos[e] = pos;
    }
}

// ---------------------------------------------------------------------------
// Score kernel (MFMA + prefetch):
//  - prefetch K[src]/Q[dst]/epos for both passes at kernel top (latency hides
//    under ea staging + MFMA),
//  - E_proj = ea_tile @ We via mfma_f32_16x16x32_bf16, +bias, stored bf16 in
//    LDS (47 KB total -> 3 blocks/CU),
//  - score phase: dot, clip, exp, write in CSR slot order.
// ---------------------------------------------------------------------------
__global__ __launch_bounds__(256, 3) void score_kernel(
    const float* __restrict__ ea,
    const int* __restrict__ ei,
    const unsigned short* __restrict__ WeT,  // [96 out][96 in] bf16
    const float* __restrict__ be,
    const float* __restrict__ Q, const float* __restrict__ K,
    const int* __restrict__ epos,
    float* __restrict__ score_s)             // [E,8] in CSR slot order
{
    __shared__ unsigned short WsT[96 * 104];  // 19968 B
    __shared__ unsigned short es[64 * 104];   // 13312 B
    __shared__ unsigned short epb[64 * 104];  // 13312 B (bf16 E_proj)
    __shared__ float bes[96];

    const int t = threadIdx.x;
    const long ebase = (long)blockIdx.x * 64;

    // ---- prefetch score-phase operands (issue-early / use-late) ----
    const int h = t & 7;
    const int el0 = t >> 3;          // 0..31
    const int el1 = 32 + el0;
    const long e0 = ebase + el0, e1 = ebase + el1;
    const int src0 = ei[e0], dst0 = ei[N_EDGES + e0];
    const int src1 = ei[e1], dst1 = ei[N_EDGES + e1];
    const int pos0 = epos[e0], pos1 = epos[e1];
    const float4* K0 = (const float4*)&K[(size_t)src0 * 96 + h * 12];
    const float4* Q0 = (const float4*)&Q[(size_t)dst0 * 96 + h * 12];
    const float4* K1 = (const float4*)&K[(size_t)src1 * 96 + h * 12];
    const float4* Q1 = (const float4*)&Q[(size_t)dst1 * 96 + h * 12];
    const float4 k0a = K0[0], k0b = K0[1], k0c = K0[2];
    const float4 q0a = Q0[0], q0b = Q0[1], q0c = Q0[2];
    const float4 k1a = K1[0], k1b = K1[1], k1c = K1[2];
    const float4 q1a = Q1[0], q1b = Q1[1], q1c = Q1[2];

    // ---- stage WeT + ea tile (bf16) ----
    for (int j = t; j < 96 * 12; j += 256) {
        const int c = j / 12, kc = j % 12;
        *(uint4*)&WsT[c * 104 + kc * 8] = *(const uint4*)&WeT[c * 96 + kc * 8];
    }
    if (t < 96) bes[t] = be[t];

    for (int j = t; j < 64 * 12; j += 256) {
        const int r = j / 12, kc = j % 12;
        const float* src = &ea[(ebase + r) * 96 + kc * 8];
        const float4 f0 = *(const float4*)src;
        const float4 f1 = *(const float4*)(src + 4);
        unsigned short b[8] = {f2bf(f0.x), f2bf(f0.y), f2bf(f0.z), f2bf(f0.w),
                               f2bf(f1.x), f2bf(f1.y), f2bf(f1.z), f2bf(f1.w)};
        *(uint4*)&es[r * 104 + kc * 8] = *(uint4*)b;
    }
    __syncthreads();

    // ---- MFMA: wave wid owns edge-rows 16*wid..+15, all 96 cols ----
    const int wid = t >> 6;
    const int lid = t & 63;
    const int l15 = lid & 15;
    const int lg  = lid >> 4;

    f32x4 acc[6] = {};
    #pragma unroll
    for (int kk = 0; kk < 3; ++kk) {
        const short8 a = *(const short8*)&es[(wid * 16 + l15) * 104 + kk * 32 + lg * 8];
        #pragma unroll
        for (int ct = 0; ct < 6; ++ct) {
            const short8 b = *(const short8*)&WsT[(ct * 16 + l15) * 104 + kk * 32 + lg * 8];
            acc[ct] = __builtin_amdgcn_mfma_f32_16x16x32_bf16(a, b, acc[ct], 0, 0, 0);
        }
    }
    // C layout: col = lane&15, row = (lane>>4)*4 + reg
    #pragma unroll
    for (int ct = 0; ct < 6; ++ct) {
        const int col = ct * 16 + l15;
        const float bias = bes[col];
        #pragma unroll
        for (int r = 0; r < 4; ++r)
            epb[(wid * 16 + lg * 4 + r) * 104 + col] = f2bf(acc[ct][r] + bias);
    }
    __syncthreads();

    // ---- score phase (uses prefetched K/Q) ----
    const float inv_sqrt_d = 0.2886751345948129f;  // 1/sqrt(12)
    #pragma unroll 2
    for (int pass = 0; pass < 2; ++pass) {
        const int el = pass ? el1 : el0;
        const int pos = pass ? pos1 : pos0;
        float kq[12];
        if (pass == 0) {
            kq[0] = k0a.x * q0a.x; kq[1] = k0a.y * q0a.y; kq[2] = k0a.z * q0a.z; kq[3] = k0a.w * q0a.w;
            kq[4] = k0b.x * q0b.x; kq[5] = k0b.y * q0b.y; kq[6] = k0b.z * q0b.z; kq[7] = k0b.w * q0b.w;
            kq[8] = k0c.x * q0c.x; kq[9] = k0c.y * q0c.y; kq[10] = k0c.z * q0c.z; kq[11] = k0c.w * q0c.w;
        } else {
            kq[0] = k1a.x * q1a.x; kq[1] = k1a.y * q1a.y; kq[2] = k1a.z * q1a.z; kq[3] = k1a.w * q1a.w;
            kq[4] = k1b.x * q1b.x; kq[5] = k1b.y * q1b.y; kq[6] = k1b.z * q1b.z; kq[7] = k1b.w * q1b.w;
            kq[8] = k1c.x * q1c.x; kq[9] = k1c.y * q1c.y; kq[10] = k1c.z * q1c.z; kq[11] = k1c.w * q1c.w;
        }
        const unsigned short* epp = &epb[el * 104 + h * 12];
        const uint2 u0 = *(const uint2*)&epp[0];
        const uint2 u1 = *(const uint2*)&epp[4];
        const uint2 u2 = *(const uint2*)&epp[8];
        float s = 0.f;
        s += kq[0] * bf2f_lo(u0.x) + kq[1] * bf2f_hi(u0.x);
        s += kq[2] * bf2f_lo(u0.y) + kq[3] * bf2f_hi(u0.y);
        s += kq[4] * bf2f_lo(u1.x) + kq[5] * bf2f_hi(u1.x);
        s += kq[6] * bf2f_lo(u1.y) + kq[7] * bf2f_hi(u1.y);
        s += kq[8] * bf2f_lo(u2.x) + kq[9] * bf2f_hi(u2.x);
        s += kq[10] * bf2f_lo(u2.y) + kq[11] * bf2f_hi(u2.y);
        s *= inv_sqrt_d;
        s = fminf(fmaxf(s, -5.f), 5.f);
        score_s[(size_t)pos * 8 + h] = expf(s);
    }
}

// ---------------------------------------------------------------------------
// Gather kernel: thread = (node, 4-col group). Sequential sorted_src/score_s
// streams; one random uint2 (4x bf16) V load per edge; unroll-2.
// ---------------------------------------------------------------------------
__global__ __launch_bounds__(256) void gather_kernel(
    const int* __restrict__ offsets, const int* __restrict__ sorted_src,
    const float* __restrict__ score_s, const unsigned short* __restrict__ Vb,
    float* __restrict__ out)
{
    const int gid = blockIdx.x * 256 + threadIdx.x;
    if (gid >= N_NODES * 24) return;
    const int n = gid / 24;
    const int c4 = gid % 24;
    const int h = c4 / 3;

    const int s0 = offsets[n];
    const int s1 = offsets[n + 1];

    float ax = 0.f, ay = 0.f, az = 0.f, aw = 0.f, z = 0.f;
    int p = s0;
    for (; p + 2 <= s1; p += 2) {
        const int srcA = sorted_src[p];
        const int srcB = sorted_src[p + 1];
        const float scA = score_s[(size_t)p * 8 + h];
        const float scB = score_s[(size_t)(p + 1) * 8 + h];
        const uint2 vA = *(const uint2*)&Vb[(size_t)srcA * 96 + c4 * 4];
        const uint2 vB = *(const uint2*)&Vb[(size_t)srcB * 96 + c4 * 4];
        ax += scA * bf2f_lo(vA.x) + scB * bf2f_lo(vB.x);
        ay += scA * bf2f_hi(vA.x) + scB * bf2f_hi(vB.x);
        az += scA * bf2f_lo(vA.y) + scB * bf2f_lo(vB.y);
        aw += scA * bf2f_hi(vA.y) + scB * bf2f_hi(vB.y);
        z  += scA + scB;
    }
    if (p < s1) {
        const int srcA = sorted_src[p];
        const float scA = score_s[(size_t)p * 8 + h];
        const uint2 vA = *(const uint2*)&Vb[(size_t)srcA * 96 + c4 * 4];
        ax += scA * bf2f_lo(vA.x);
        ay += scA * bf2f_hi(vA.x);
        az += scA * bf2f_lo(vA.y);
        aw += scA * bf2f_hi(vA.y);
        z  += scA;
    }
    const float inv = 1.f / (z + 1e-6f);
    *(float4*)&out[(size_t)n * 96 + c4 * 4] =
        make_float4(ax * inv, ay * inv, az * inv, aw * inv);
}

// ---------------------------------------------------------------------------
extern "C" void kernel_launch(void* const* d_in, const int* in_sizes, int n_in,
                              void* d_out, int out_size, void* d_ws, size_t ws_size,
                              hipStream_t stream) {
    const float* x  = (const float*)d_in[0];
    const int*   ei = (const int*)d_in[1];   // [2, E] int32 (JAX x64 disabled)
    const float* ea = (const float*)d_in[2];
    const float* Wq = (const float*)d_in[3];
    const float* bq = (const float*)d_in[4];
    const float* Wk = (const float*)d_in[5];
    const float* bk = (const float*)d_in[6];
    const float* We = (const float*)d_in[7];
    const float* be = (const float*)d_in[8];
    const float* Wv = (const float*)d_in[9];
    const float* bv = (const float*)d_in[10];

    float* out = (float*)d_out;

    // workspace: Q | K | Vb(bf16 in float-sized slot) | score_s | offsets |
    //            cursor | epos | sorted_src | WeT
    const size_t nqkv = (size_t)N_NODES * 96;
    float* Q       = (float*)d_ws;
    float* K       = Q + nqkv;
    unsigned short* Vb = (unsigned short*)(K + nqkv);         // [N*96] bf16
    float* score_s = (K + nqkv) + nqkv;                       // [E,8]
    int* offsets    = (int*)(score_s + (size_t)N_EDGES * 8);  // [N+1]
    int* cursor     = offsets + (N_NODES + 1);                // [N]
    int* epos       = cursor + N_NODES;                       // [E]
    int* sorted_src = epos + N_EDGES;                         // [E]
    unsigned short* WeT = (unsigned short*)(sorted_src + N_EDGES);  // [96*96]

    hipMemsetAsync(cursor, 0, N_NODES * sizeof(int), stream);

    wet_kernel<<<dim3(36), 256, 0, stream>>>(We, WeT);

    qkv_kernel<<<dim3((N_NODES + 63) / 64), 256, 0, stream>>>(
        x, Wq, bq, Wk, bk, Wv, bv, Q, K, Vb);

    hist_kernel<<<dim3((N_EDGES + 255) / 256), 256, 0, stream>>>(ei, cursor);
    scan_kernel<<<dim3(1), 1024, 0, stream>>>(cursor, offsets);
    scatter_kernel<<<dim3((N_EDGES + 255) / 256), 256, 0, stream>>>(
        ei, cursor, sorted_src, epos);

    score_kernel<<<dim3(N_EDGES / 64), 256, 0, stream>>>(
        ea, ei, WeT, be, Q, K, epos, score_s);

    gather_kernel<<<dim3((N_NODES * 24 + 255) / 256), 256, 0, stream>>>(
        offsets, sorted_src, score_s, Vb, out);
}

// Round 6
// 447.841 us; speedup vs baseline: 7.7924x; 1.0840x over previous
//
#include <hip/hip_runtime.h>
#include <math.h>

#define N_NODES 50000
#define N_EDGES 800000
#define IN_DIM 96
#define NHEADS 8
#define HDIM 12

typedef __attribute__((ext_vector_type(8))) short short8;
typedef __attribute__((ext_vector_type(4))) float f32x4;

__device__ __forceinline__ unsigned short f2bf(float f) {
    unsigned int u = __float_as_uint(f);
    return (unsigned short)((u + 0x7FFFu + ((u >> 16) & 1u)) >> 16);
}
__device__ __forceinline__ float bf2f_lo(unsigned int u) {
    return __uint_as_float(u << 16);
}
__device__ __forceinline__ float bf2f_hi(unsigned int u) {
    return __uint_as_float(u & 0xFFFF0000u);
}
__device__ __forceinline__ unsigned int pack2(float a, float b) {
    return (unsigned int)f2bf(a) | ((unsigned int)f2bf(b) << 16);
}

// ---------------------------------------------------------------------------
// Kernel 1: Q/K/V projections, fp32 math, register-blocked.
// ALL outputs written bf16 (score reads K/Q randomly, gather reads V
// randomly -> halve the random-read bytes and the store traffic).
// ---------------------------------------------------------------------------
__global__ __launch_bounds__(256) void qkv_kernel(
    const float* __restrict__ x,
    const float* __restrict__ Wq, const float* __restrict__ bq,
    const float* __restrict__ Wk, const float* __restrict__ bk,
    const float* __restrict__ Wv, const float* __restrict__ bv,
    unsigned short* __restrict__ Qb, unsigned short* __restrict__ Kb,
    unsigned short* __restrict__ Vb)
{
    __shared__ float xs[96][68];   // transposed, pad 64->68
    __shared__ float Ws[96 * 96];
    __shared__ float bs[96];

    const int t = threadIdx.x;
    const int nbase = blockIdx.x * 64;

    for (int j = t; j < 64 * 24; j += 256) {
        const int r = j / 24, c4 = j % 24;
        const int n = nbase + r;
        float4 val = make_float4(0.f, 0.f, 0.f, 0.f);
        if (n < N_NODES) val = *(const float4*)&x[(size_t)n * 96 + c4 * 4];
        xs[c4 * 4 + 0][r] = val.x;
        xs[c4 * 4 + 1][r] = val.y;
        xs[c4 * 4 + 2][r] = val.z;
        xs[c4 * 4 + 3][r] = val.w;
    }

    const int np = t & 15;   // nodes np*4 .. np*4+3
    const int tc = t >> 4;   // cols tc*6 .. tc*6+5

    const float* Wlist[3] = {Wq, Wk, Wv};
    const float* blist[3] = {bq, bk, bv};

    for (int w = 0; w < 3; ++w) {
        __syncthreads();
        const float4* Wg = (const float4*)Wlist[w];
        for (int j = t; j < 2304; j += 256) ((float4*)Ws)[j] = Wg[j];
        if (t < 96) bs[t] = blist[w][t];
        __syncthreads();

        float acc0[6], acc1[6], acc2[6], acc3[6];
        #pragma unroll
        for (int d = 0; d < 6; ++d) {
            const float b = bs[tc * 6 + d];
            acc0[d] = b; acc1[d] = b; acc2[d] = b; acc3[d] = b;
        }

        for (int i = 0; i < 96; ++i) {
            const float4 xv = *(const float4*)&xs[i][np * 4];
            const float2 wa = *(const float2*)&Ws[i * 96 + tc * 6];
            const float2 wb = *(const float2*)&Ws[i * 96 + tc * 6 + 2];
            const float2 wc = *(const float2*)&Ws[i * 96 + tc * 6 + 4];
            const float wv[6] = {wa.x, wa.y, wb.x, wb.y, wc.x, wc.y};
            #pragma unroll
            for (int d = 0; d < 6; ++d) {
                acc0[d] += xv.x * wv[d];
                acc1[d] += xv.y * wv[d];
                acc2[d] += xv.z * wv[d];
                acc3[d] += xv.w * wv[d];
            }
        }

        unsigned short* Ob = (w == 0) ? Qb : (w == 1) ? Kb : Vb;
        #pragma unroll
        for (int r = 0; r < 4; ++r) {
            const int n = nbase + np * 4 + r;
            if (n >= N_NODES) continue;
            const float* ap = (r == 0) ? acc0 : (r == 1) ? acc1 : (r == 2) ? acc2 : acc3;
            unsigned int* dst = (unsigned int*)&Ob[(size_t)n * 96 + tc * 6];
            dst[0] = pack2(ap[0], ap[1]);
            dst[1] = pack2(ap[2], ap[3]);
            dst[2] = pack2(ap[4], ap[5]);
        }
    }
}

// ---------------------------------------------------------------------------
// Setup: We [96(in)][96(out)] fp32 -> WeT [96(out)][96(in)] bf16
// ---------------------------------------------------------------------------
__global__ __launch_bounds__(256) void wet_kernel(
    const float* __restrict__ We, unsigned short* __restrict__ WeT)
{
    const int j = blockIdx.x * 256 + threadIdx.x;
    if (j < 96 * 96) {
        const int k = j / 96, c = j % 96;
        WeT[c * 96 + k] = f2bf(We[j]);
    }
}

// ---------------------------------------------------------------------------
// CSR build: histogram -> single-block scan. (Scatter is fused into score.)
// ---------------------------------------------------------------------------
__global__ __launch_bounds__(256) void hist_kernel(
    const int* __restrict__ ei, int* __restrict__ cursor)
{
    const int e = blockIdx.x * 256 + threadIdx.x;
    if (e < N_EDGES) atomicAdd(&cursor[ei[N_EDGES + e]], 1);
}

__global__ __launch_bounds__(1024) void scan_kernel(
    int* __restrict__ cursor, int* __restrict__ offsets)
{
    __shared__ int tsum[1024];
    const int t = threadIdx.x;
    const int CH = (N_NODES + 1023) / 1024;  // 49
    const int base = t * CH;

    int s = 0;
    for (int i = 0; i < CH; ++i) {
        const int idx = base + i;
        if (idx < N_NODES) s += cursor[idx];
    }
    tsum[t] = s;
    __syncthreads();
    for (int off = 1; off < 1024; off <<= 1) {
        const int v = (t >= off) ? tsum[t - off] : 0;
        __syncthreads();
        tsum[t] += v;
        __syncthreads();
    }
    int run = (t == 0) ? 0 : tsum[t - 1];
    for (int i = 0; i < CH; ++i) {
        const int idx = base + i;
        if (idx < N_NODES) {
            const int c = cursor[idx];
            cursor[idx] = run;       // scatter cursor (start offsets)
            offsets[idx] = run;      // CSR offsets for gather
            run += c;
        }
    }
    if (t == 1023) offsets[N_NODES] = run;
}

// ---------------------------------------------------------------------------
// Score kernel (MFMA + prefetch + fused CSR scatter):
//  - prefetch bf16 K[src]/Q[dst] rows; h==0 lane claims CSR slot via
//    atomicAdd(cursor[dst]) and writes sorted_src; pos broadcast via shfl,
//  - E_proj = ea_tile @ We via mfma_f32_16x16x32_bf16, +bias, bf16 in LDS,
//  - score phase: dot(K*Q*E)/sqrt(12), clip, exp, write in CSR slot order.
// ---------------------------------------------------------------------------
__global__ __launch_bounds__(256, 3) void score_kernel(
    const float* __restrict__ ea,
    const int* __restrict__ ei,
    const unsigned short* __restrict__ WeT,  // [96 out][96 in] bf16
    const float* __restrict__ be,
    const unsigned short* __restrict__ Qb, const unsigned short* __restrict__ Kb,
    int* __restrict__ cursor,
    int* __restrict__ sorted_src,
    float* __restrict__ score_s)             // [E,8] in CSR slot order
{
    __shared__ unsigned short WsT[96 * 104];  // 19968 B
    __shared__ unsigned short es[64 * 104];   // 13312 B
    __shared__ unsigned short epb[64 * 104];  // 13312 B (bf16 E_proj)
    __shared__ float bes[96];

    const int t = threadIdx.x;
    const long ebase = (long)blockIdx.x * 64;

    // ---- prefetch score-phase operands (issue-early / use-late) ----
    const int h = t & 7;
    const int el0 = t >> 3;          // 0..31
    const int el1 = 32 + el0;
    const long e0 = ebase + el0, e1 = ebase + el1;
    const int src0 = ei[e0], dst0 = ei[N_EDGES + e0];
    const int src1 = ei[e1], dst1 = ei[N_EDGES + e1];

    const uint2* K0 = (const uint2*)&Kb[(size_t)src0 * 96 + h * 12];
    const uint2* Q0 = (const uint2*)&Qb[(size_t)dst0 * 96 + h * 12];
    const uint2* K1 = (const uint2*)&Kb[(size_t)src1 * 96 + h * 12];
    const uint2* Q1 = (const uint2*)&Qb[(size_t)dst1 * 96 + h * 12];
    const uint2 k0a = K0[0], k0b = K0[1], k0c = K0[2];
    const uint2 q0a = Q0[0], q0b = Q0[1], q0c = Q0[2];
    const uint2 k1a = K1[0], k1b = K1[1], k1c = K1[2];
    const uint2 q1a = Q1[0], q1b = Q1[1], q1c = Q1[2];

    // fused CSR scatter: one atomic per edge, pos broadcast to the 8 lanes
    int pos0 = 0, pos1 = 0;
    if (h == 0) {
        pos0 = atomicAdd(&cursor[dst0], 1);
        pos1 = atomicAdd(&cursor[dst1], 1);
        sorted_src[pos0] = src0;
        sorted_src[pos1] = src1;
    }
    pos0 = __shfl(pos0, 0, 8);
    pos1 = __shfl(pos1, 0, 8);

    // ---- stage WeT + ea tile (bf16) ----
    for (int j = t; j < 96 * 12; j += 256) {
        const int c = j / 12, kc = j % 12;
        *(uint4*)&WsT[c * 104 + kc * 8] = *(const uint4*)&WeT[c * 96 + kc * 8];
    }
    if (t < 96) bes[t] = be[t];

    for (int j = t; j < 64 * 12; j += 256) {
        const int r = j / 12, kc = j % 12;
        const float* src = &ea[(ebase + r) * 96 + kc * 8];
        const float4 f0 = *(const float4*)src;
        const float4 f1 = *(const float4*)(src + 4);
        unsigned short b[8] = {f2bf(f0.x), f2bf(f0.y), f2bf(f0.z), f2bf(f0.w),
                               f2bf(f1.x), f2bf(f1.y), f2bf(f1.z), f2bf(f1.w)};
        *(uint4*)&es[r * 104 + kc * 8] = *(uint4*)b;
    }
    __syncthreads();

    // ---- MFMA: wave wid owns edge-rows 16*wid..+15, all 96 cols ----
    const int wid = t >> 6;
    const int lid = t & 63;
    const int l15 = lid & 15;
    const int lg  = lid >> 4;

    f32x4 acc[6] = {};
    #pragma unroll
    for (int kk = 0; kk < 3; ++kk) {
        const short8 a = *(const short8*)&es[(wid * 16 + l15) * 104 + kk * 32 + lg * 8];
        #pragma unroll
        for (int ct = 0; ct < 6; ++ct) {
            const short8 b = *(const short8*)&WsT[(ct * 16 + l15) * 104 + kk * 32 + lg * 8];
            acc[ct] = __builtin_amdgcn_mfma_f32_16x16x32_bf16(a, b, acc[ct], 0, 0, 0);
        }
    }
    // C layout: col = lane&15, row = (lane>>4)*4 + reg
    #pragma unroll
    for (int ct = 0; ct < 6; ++ct) {
        const int col = ct * 16 + l15;
        const float bias = bes[col];
        #pragma unroll
        for (int r = 0; r < 4; ++r)
            epb[(wid * 16 + lg * 4 + r) * 104 + col] = f2bf(acc[ct][r] + bias);
    }
    __syncthreads();

    // ---- score phase (prefetched bf16 K/Q vs bf16 ep in LDS) ----
    const float inv_sqrt_d = 0.2886751345948129f;  // 1/sqrt(12)
#define ACC3(KU, QU, EU) \
    s += bf2f_lo(KU) * bf2f_lo(QU) * bf2f_lo(EU) + \
         bf2f_hi(KU) * bf2f_hi(QU) * bf2f_hi(EU);

    #pragma unroll 2
    for (int pass = 0; pass < 2; ++pass) {
        const int el = pass ? el1 : el0;
        const int pos = pass ? pos1 : pos0;
        const unsigned short* epp = &epb[el * 104 + h * 12];
        const uint2 u0 = *(const uint2*)&epp[0];
        const uint2 u1 = *(const uint2*)&epp[4];
        const uint2 u2 = *(const uint2*)&epp[8];
        float s = 0.f;
        if (pass == 0) {
            ACC3(k0a.x, q0a.x, u0.x); ACC3(k0a.y, q0a.y, u0.y);
            ACC3(k0b.x, q0b.x, u1.x); ACC3(k0b.y, q0b.y, u1.y);
            ACC3(k0c.x, q0c.x, u2.x); ACC3(k0c.y, q0c.y, u2.y);
        } else {
            ACC3(k1a.x, q1a.x, u0.x); ACC3(k1a.y, q1a.y, u0.y);
            ACC3(k1b.x, q1b.x, u1.x); ACC3(k1b.y, q1b.y, u1.y);
            ACC3(k1c.x, q1c.x, u2.x); ACC3(k1c.y, q1c.y, u2.y);
        }
        s *= inv_sqrt_d;
        s = fminf(fmaxf(s, -5.f), 5.f);
        score_s[(size_t)pos * 8 + h] = expf(s);
    }
#undef ACC3
}

// ---------------------------------------------------------------------------
// Gather kernel: thread = (node, 24-col group g). Heads 2g, 2g+1 exactly.
// Per edge: 1 src + 1 float2 (both heads' scores) + 3 uint4 V loads; unroll-2.
// ---------------------------------------------------------------------------
__global__ __launch_bounds__(256) void gather_kernel(
    const int* __restrict__ offsets, const int* __restrict__ sorted_src,
    const float* __restrict__ score_s, const unsigned short* __restrict__ Vb,
    float* __restrict__ out)
{
    const int gid = blockIdx.x * 256 + threadIdx.x;
    if (gid >= N_NODES * 4) return;
    const int n = gid >> 2;
    const int g = gid & 3;           // cols g*24 .. g*24+23, heads 2g, 2g+1

    const int s0 = offsets[n];
    const int s1 = offsets[n + 1];

    float acc[24];
    #pragma unroll
    for (int i = 0; i < 24; ++i) acc[i] = 0.f;
    float z0 = 0.f, z1 = 0.f;

#define ACCUM(U0, U1, U2, SC) \
    acc[0]  += SC.x * bf2f_lo(U0.x); acc[1]  += SC.x * bf2f_hi(U0.x); \
    acc[2]  += SC.x * bf2f_lo(U0.y); acc[3]  += SC.x * bf2f_hi(U0.y); \
    acc[4]  += SC.x * bf2f_lo(U0.z); acc[5]  += SC.x * bf2f_hi(U0.z); \
    acc[6]  += SC.x * bf2f_lo(U0.w); acc[7]  += SC.x * bf2f_hi(U0.w); \
    acc[8]  += SC.x * bf2f_lo(U1.x); acc[9]  += SC.x * bf2f_hi(U1.x); \
    acc[10] += SC.x * bf2f_lo(U1.y); acc[11] += SC.x * bf2f_hi(U1.y); \
    acc[12] += SC.y * bf2f_lo(U1.z); acc[13] += SC.y * bf2f_hi(U1.z); \
    acc[14] += SC.y * bf2f_lo(U1.w); acc[15] += SC.y * bf2f_hi(U1.w); \
    acc[16] += SC.y * bf2f_lo(U2.x); acc[17] += SC.y * bf2f_hi(U2.x); \
    acc[18] += SC.y * bf2f_lo(U2.y); acc[19] += SC.y * bf2f_hi(U2.y); \
    acc[20] += SC.y * bf2f_lo(U2.z); acc[21] += SC.y * bf2f_hi(U2.z); \
    acc[22] += SC.y * bf2f_lo(U2.w); acc[23] += SC.y * bf2f_hi(U2.w);

    int p = s0;
    for (; p + 2 <= s1; p += 2) {
        const int srcA = sorted_src[p];
        const int srcB = sorted_src[p + 1];
        const float2 scA = *(const float2*)&score_s[(size_t)p * 8 + g * 2];
        const float2 scB = *(const float2*)&score_s[(size_t)(p + 1) * 8 + g * 2];
        const uint4* VA = (const uint4*)&Vb[(size_t)srcA * 96 + g * 24];
        const uint4* VB = (const uint4*)&Vb[(size_t)srcB * 96 + g * 24];
        const uint4 a0 = VA[0], a1 = VA[1], a2 = VA[2];
        const uint4 b0 = VB[0], b1 = VB[1], b2 = VB[2];
        ACCUM(a0, a1, a2, scA);
        ACCUM(b0, b1, b2, scB);
        z0 += scA.x + scB.x;
        z1 += scA.y + scB.y;
    }
    if (p < s1) {
        const int srcA = sorted_src[p];
        const float2 scA = *(const float2*)&score_s[(size_t)p * 8 + g * 2];
        const uint4* VA = (const uint4*)&Vb[(size_t)srcA * 96 + g * 24];
        const uint4 a0 = VA[0], a1 = VA[1], a2 = VA[2];
        ACCUM(a0, a1, a2, scA);
        z0 += scA.x;
        z1 += scA.y;
    }
#undef ACCUM

    const float i0 = 1.f / (z0 + 1e-6f);
    const float i1 = 1.f / (z1 + 1e-6f);
    float o[24];
    #pragma unroll
    for (int k = 0; k < 24; ++k) o[k] = acc[k] * (k < 12 ? i0 : i1);
    float* dst = &out[(size_t)n * 96 + g * 24];
    #pragma unroll
    for (int k = 0; k < 6; ++k)
        *(float4*)&dst[k * 4] = make_float4(o[k*4], o[k*4+1], o[k*4+2], o[k*4+3]);
}

// ---------------------------------------------------------------------------
extern "C" void kernel_launch(void* const* d_in, const int* in_sizes, int n_in,
                              void* d_out, int out_size, void* d_ws, size_t ws_size,
                              hipStream_t stream) {
    const float* x  = (const float*)d_in[0];
    const int*   ei = (const int*)d_in[1];   // [2, E] int32 (JAX x64 disabled)
    const float* ea = (const float*)d_in[2];
    const float* Wq = (const float*)d_in[3];
    const float* bq = (const float*)d_in[4];
    const float* Wk = (const float*)d_in[5];
    const float* bk = (const float*)d_in[6];
    const float* We = (const float*)d_in[7];
    const float* be = (const float*)d_in[8];
    const float* Wv = (const float*)d_in[9];
    const float* bv = (const float*)d_in[10];

    float* out = (float*)d_out;

    // workspace: Qb | Kb | Vb (bf16) | score_s | offsets | cursor | sorted_src | WeT
    const size_t nqkv = (size_t)N_NODES * 96;
    unsigned short* Qb = (unsigned short*)d_ws;
    unsigned short* Kb = Qb + nqkv;
    unsigned short* Vb = Kb + nqkv;
    float* score_s  = (float*)(Vb + nqkv);                   // [E,8]
    int* offsets    = (int*)(score_s + (size_t)N_EDGES * 8); // [N+1]
    int* cursor     = offsets + (N_NODES + 1);               // [N]
    int* sorted_src = cursor + N_NODES;                      // [E]
    unsigned short* WeT = (unsigned short*)(sorted_src + N_EDGES);  // [96*96]

    hipMemsetAsync(cursor, 0, N_NODES * sizeof(int), stream);

    wet_kernel<<<dim3(36), 256, 0, stream>>>(We, WeT);

    qkv_kernel<<<dim3((N_NODES + 63) / 64), 256, 0, stream>>>(
        x, Wq, bq, Wk, bk, Wv, bv, Qb, Kb, Vb);

    hist_kernel<<<dim3((N_EDGES + 255) / 256), 256, 0, stream>>>(ei, cursor);
    scan_kernel<<<dim3(1), 1024, 0, stream>>>(cursor, offsets);

    score_kernel<<<dim3(N_EDGES / 64), 256, 0, stream>>>(
        ea, ei, WeT, be, Qb, Kb, cursor, sorted_src, score_s);

    gather_kernel<<<dim3((N_NODES * 4 + 255) / 256), 256, 0, stream>>>(
        offsets, sorted_src, score_s, Vb, out);
}

// Round 7
// 409.463 us; speedup vs baseline: 8.5228x; 1.0937x over previous
//
#include <hip/hip_runtime.h>
#include <math.h>

#define N_NODES 50000
#define N_EDGES 800000
#define IN_DIM 96
#define NHEADS 8
#define HDIM 12

typedef __attribute__((ext_vector_type(8))) short short8;
typedef __attribute__((ext_vector_type(4))) float f32x4;

__device__ __forceinline__ unsigned short f2bf(float f) {
    unsigned int u = __float_as_uint(f);
    return (unsigned short)((u + 0x7FFFu + ((u >> 16) & 1u)) >> 16);
}
__device__ __forceinline__ float bf2f_lo(unsigned int u) {
    return __uint_as_float(u << 16);
}
__device__ __forceinline__ float bf2f_hi(unsigned int u) {
    return __uint_as_float(u & 0xFFFF0000u);
}
__device__ __forceinline__ unsigned int pack2(float a, float b) {
    return (unsigned int)f2bf(a) | ((unsigned int)f2bf(b) << 16);
}
__device__ __forceinline__ short8 pack8(const float4 lo, const float4 hi) {
    union { uint4 u; short8 s; } c;
    c.u.x = pack2(lo.x, lo.y);
    c.u.y = pack2(lo.z, lo.w);
    c.u.z = pack2(hi.x, hi.y);
    c.u.w = pack2(hi.z, hi.w);
    return c.s;
}

// ---------------------------------------------------------------------------
// Kernel 1: Q/K/V projections, fp32 math, register-blocked; bf16 outputs.
// ---------------------------------------------------------------------------
__global__ __launch_bounds__(256) void qkv_kernel(
    const float* __restrict__ x,
    const float* __restrict__ Wq, const float* __restrict__ bq,
    const float* __restrict__ Wk, const float* __restrict__ bk,
    const float* __restrict__ Wv, const float* __restrict__ bv,
    unsigned short* __restrict__ Qb, unsigned short* __restrict__ Kb,
    unsigned short* __restrict__ Vb)
{
    __shared__ float xs[96][68];   // transposed, pad 64->68
    __shared__ float Ws[96 * 96];
    __shared__ float bs[96];

    const int t = threadIdx.x;
    const int nbase = blockIdx.x * 64;

    for (int j = t; j < 64 * 24; j += 256) {
        const int r = j / 24, c4 = j % 24;
        const int n = nbase + r;
        float4 val = make_float4(0.f, 0.f, 0.f, 0.f);
        if (n < N_NODES) val = *(const float4*)&x[(size_t)n * 96 + c4 * 4];
        xs[c4 * 4 + 0][r] = val.x;
        xs[c4 * 4 + 1][r] = val.y;
        xs[c4 * 4 + 2][r] = val.z;
        xs[c4 * 4 + 3][r] = val.w;
    }

    const int np = t & 15;   // nodes np*4 .. np*4+3
    const int tc = t >> 4;   // cols tc*6 .. tc*6+5

    const float* Wlist[3] = {Wq, Wk, Wv};
    const float* blist[3] = {bq, bk, bv};

    for (int w = 0; w < 3; ++w) {
        __syncthreads();
        const float4* Wg = (const float4*)Wlist[w];
        for (int j = t; j < 2304; j += 256) ((float4*)Ws)[j] = Wg[j];
        if (t < 96) bs[t] = blist[w][t];
        __syncthreads();

        float acc0[6], acc1[6], acc2[6], acc3[6];
        #pragma unroll
        for (int d = 0; d < 6; ++d) {
            const float b = bs[tc * 6 + d];
            acc0[d] = b; acc1[d] = b; acc2[d] = b; acc3[d] = b;
        }

        for (int i = 0; i < 96; ++i) {
            const float4 xv = *(const float4*)&xs[i][np * 4];
            const float2 wa = *(const float2*)&Ws[i * 96 + tc * 6];
            const float2 wb = *(const float2*)&Ws[i * 96 + tc * 6 + 2];
            const float2 wc = *(const float2*)&Ws[i * 96 + tc * 6 + 4];
            const float wv[6] = {wa.x, wa.y, wb.x, wb.y, wc.x, wc.y};
            #pragma unroll
            for (int d = 0; d < 6; ++d) {
                acc0[d] += xv.x * wv[d];
                acc1[d] += xv.y * wv[d];
                acc2[d] += xv.z * wv[d];
                acc3[d] += xv.w * wv[d];
            }
        }

        unsigned short* Ob = (w == 0) ? Qb : (w == 1) ? Kb : Vb;
        #pragma unroll
        for (int r = 0; r < 4; ++r) {
            const int n = nbase + np * 4 + r;
            if (n >= N_NODES) continue;
            const float* ap = (r == 0) ? acc0 : (r == 1) ? acc1 : (r == 2) ? acc2 : acc3;
            unsigned int* dst = (unsigned int*)&Ob[(size_t)n * 96 + tc * 6];
            dst[0] = pack2(ap[0], ap[1]);
            dst[1] = pack2(ap[2], ap[3]);
            dst[2] = pack2(ap[4], ap[5]);
        }
    }
}

// ---------------------------------------------------------------------------
// Setup: We [96(in)][96(out)] fp32 -> WeT [96(out)][96(in)] bf16
// ---------------------------------------------------------------------------
__global__ __launch_bounds__(256) void wet_kernel(
    const float* __restrict__ We, unsigned short* __restrict__ WeT)
{
    const int j = blockIdx.x * 256 + threadIdx.x;
    if (j < 96 * 96) {
        const int k = j / 96, c = j % 96;
        WeT[c * 96 + k] = f2bf(We[j]);
    }
}

// ---------------------------------------------------------------------------
// CSR build: histogram -> single-block scan. (Scatter fused into score.)
// ---------------------------------------------------------------------------
__global__ __launch_bounds__(256) void hist_kernel(
    const int* __restrict__ ei, int* __restrict__ cursor)
{
    const int e = blockIdx.x * 256 + threadIdx.x;
    if (e < N_EDGES) atomicAdd(&cursor[ei[N_EDGES + e]], 1);
}

__global__ __launch_bounds__(1024) void scan_kernel(
    int* __restrict__ cursor, int* __restrict__ offsets)
{
    __shared__ int tsum[1024];
    const int t = threadIdx.x;
    const int CH = (N_NODES + 1023) / 1024;  // 49
    const int base = t * CH;

    int s = 0;
    for (int i = 0; i < CH; ++i) {
        const int idx = base + i;
        if (idx < N_NODES) s += cursor[idx];
    }
    tsum[t] = s;
    __syncthreads();
    for (int off = 1; off < 1024; off <<= 1) {
        const int v = (t >= off) ? tsum[t - off] : 0;
        __syncthreads();
        tsum[t] += v;
        __syncthreads();
    }
    int run = (t == 0) ? 0 : tsum[t - 1];
    for (int i = 0; i < CH; ++i) {
        const int idx = base + i;
        if (idx < N_NODES) {
            const int c = cursor[idx];
            cursor[idx] = run;       // scatter cursor (start offsets)
            offsets[idx] = run;      // CSR offsets for gather
            run += c;
        }
    }
    if (t == 1023) offsets[N_NODES] = run;
}

// ---------------------------------------------------------------------------
// Score kernel (MFMA, direct-A, prefetch, fused CSR scatter):
//  - A-fragments of ea loaded straight global->reg (no es LDS, one fewer
//    LDS round-trip; 33.7 KB LDS -> 4 blocks/CU),
//  - prefetch bf16 K[src]/Q[dst]; h==0 lane claims CSR slot via atomicAdd,
//  - E_proj = ea_tile @ We via mfma_f32_16x16x32_bf16, +bias, bf16 in LDS,
//  - score phase: dot(K*Q*E)/sqrt(12), clip, exp, write in CSR slot order.
// ---------------------------------------------------------------------------
__global__ __launch_bounds__(256, 4) void score_kernel(
    const float* __restrict__ ea,
    const int* __restrict__ ei,
    const unsigned short* __restrict__ WeT,  // [96 out][96 in] bf16
    const float* __restrict__ be,
    const unsigned short* __restrict__ Qb, const unsigned short* __restrict__ Kb,
    int* __restrict__ cursor,
    int* __restrict__ sorted_src,
    float* __restrict__ score_s)             // [E,8] in CSR slot order
{
    __shared__ unsigned short WsT[96 * 104];  // 19968 B
    __shared__ unsigned short epb[64 * 104];  // 13312 B (bf16 E_proj)
    __shared__ float bes[96];                 // total ~33.7 KB

    const int t = threadIdx.x;
    const long ebase = (long)blockIdx.x * 64;

    const int wid = t >> 6;
    const int lid = t & 63;
    const int l15 = lid & 15;
    const int lg  = lid >> 4;

    // ---- issue edge-index loads first (longest dependent chain) ----
    const int h = t & 7;
    const int el0 = t >> 3;          // 0..31
    const int el1 = 32 + el0;
    const long e0 = ebase + el0, e1 = ebase + el1;
    const int src0 = ei[e0], dst0 = ei[N_EDGES + e0];
    const int src1 = ei[e1], dst1 = ei[N_EDGES + e1];

    // ---- A-fragment loads: lane owns row wid*16+l15, col-chunks lg*8 ----
    const float* arow = &ea[(ebase + wid * 16 + l15) * 96 + lg * 8];
    const float4 a0lo = *(const float4*)(arow + 0);
    const float4 a0hi = *(const float4*)(arow + 4);
    const float4 a1lo = *(const float4*)(arow + 32);
    const float4 a1hi = *(const float4*)(arow + 36);
    const float4 a2lo = *(const float4*)(arow + 64);
    const float4 a2hi = *(const float4*)(arow + 68);

    // ---- stage WsT (L2-resident, same for all blocks) ----
    for (int j = t; j < 96 * 12; j += 256) {
        const int c = j / 12, kc = j % 12;
        *(uint4*)&WsT[c * 104 + kc * 8] = *(const uint4*)&WeT[c * 96 + kc * 8];
    }
    if (t < 96) bes[t] = be[t];

    // ---- K/Q prefetch (dependent on ei) ----
    const uint2* K0 = (const uint2*)&Kb[(size_t)src0 * 96 + h * 12];
    const uint2* Q0 = (const uint2*)&Qb[(size_t)dst0 * 96 + h * 12];
    const uint2* K1 = (const uint2*)&Kb[(size_t)src1 * 96 + h * 12];
    const uint2* Q1 = (const uint2*)&Qb[(size_t)dst1 * 96 + h * 12];
    const uint2 k0a = K0[0], k0b = K0[1], k0c = K0[2];
    const uint2 q0a = Q0[0], q0b = Q0[1], q0c = Q0[2];
    const uint2 k1a = K1[0], k1b = K1[1], k1c = K1[2];
    const uint2 q1a = Q1[0], q1b = Q1[1], q1c = Q1[2];

    // fused CSR scatter: one atomic per edge, pos broadcast to the 8 lanes
    int pos0 = 0, pos1 = 0;
    if (h == 0) {
        pos0 = atomicAdd(&cursor[dst0], 1);
        pos1 = atomicAdd(&cursor[dst1], 1);
        sorted_src[pos0] = src0;
        sorted_src[pos1] = src1;
    }
    pos0 = __shfl(pos0, 0, 8);
    pos1 = __shfl(pos1, 0, 8);

    __syncthreads();   // WsT ready

    // ---- MFMA: wave wid owns edge-rows 16*wid..+15, all 96 cols ----
    const short8 af[3] = {pack8(a0lo, a0hi), pack8(a1lo, a1hi), pack8(a2lo, a2hi)};

    f32x4 acc[6] = {};
    #pragma unroll
    for (int kk = 0; kk < 3; ++kk) {
        #pragma unroll
        for (int ct = 0; ct < 6; ++ct) {
            const short8 b = *(const short8*)&WsT[(ct * 16 + l15) * 104 + kk * 32 + lg * 8];
            acc[ct] = __builtin_amdgcn_mfma_f32_16x16x32_bf16(af[kk], b, acc[ct], 0, 0, 0);
        }
    }
    // C layout: col = lane&15, row = (lane>>4)*4 + reg
    #pragma unroll
    for (int ct = 0; ct < 6; ++ct) {
        const int col = ct * 16 + l15;
        const float bias = bes[col];
        #pragma unroll
        for (int r = 0; r < 4; ++r)
            epb[(wid * 16 + lg * 4 + r) * 104 + col] = f2bf(acc[ct][r] + bias);
    }
    __syncthreads();

    // ---- score phase (prefetched bf16 K/Q vs bf16 ep in LDS) ----
    const float inv_sqrt_d = 0.2886751345948129f;  // 1/sqrt(12)
#define ACC3(KU, QU, EU) \
    s += bf2f_lo(KU) * bf2f_lo(QU) * bf2f_lo(EU) + \
         bf2f_hi(KU) * bf2f_hi(QU) * bf2f_hi(EU);

    #pragma unroll 2
    for (int pass = 0; pass < 2; ++pass) {
        const int el = pass ? el1 : el0;
        const int pos = pass ? pos1 : pos0;
        const unsigned short* epp = &epb[el * 104 + h * 12];
        const uint2 u0 = *(const uint2*)&epp[0];
        const uint2 u1 = *(const uint2*)&epp[4];
        const uint2 u2 = *(const uint2*)&epp[8];
        float s = 0.f;
        if (pass == 0) {
            ACC3(k0a.x, q0a.x, u0.x); ACC3(k0a.y, q0a.y, u0.y);
            ACC3(k0b.x, q0b.x, u1.x); ACC3(k0b.y, q0b.y, u1.y);
            ACC3(k0c.x, q0c.x, u2.x); ACC3(k0c.y, q0c.y, u2.y);
        } else {
            ACC3(k1a.x, q1a.x, u0.x); ACC3(k1a.y, q1a.y, u0.y);
            ACC3(k1b.x, q1b.x, u1.x); ACC3(k1b.y, q1b.y, u1.y);
            ACC3(k1c.x, q1c.x, u2.x); ACC3(k1c.y, q1c.y, u2.y);
        }
        s *= inv_sqrt_d;
        s = fminf(fmaxf(s, -5.f), 5.f);
        score_s[(size_t)pos * 8 + h] = expf(s);
    }
#undef ACC3
}

// ---------------------------------------------------------------------------
// Gather kernel: thread = (node, 24-col group g). Heads 2g, 2g+1 exactly.
// Per edge: 1 src + 1 float2 (both heads' scores) + 3 uint4 V loads; unroll-2.
// ---------------------------------------------------------------------------
__global__ __launch_bounds__(256) void gather_kernel(
    const int* __restrict__ offsets, const int* __restrict__ sorted_src,
    const float* __restrict__ score_s, const unsigned short* __restrict__ Vb,
    float* __restrict__ out)
{
    const int gid = blockIdx.x * 256 + threadIdx.x;
    if (gid >= N_NODES * 4) return;
    const int n = gid >> 2;
    const int g = gid & 3;           // cols g*24 .. g*24+23, heads 2g, 2g+1

    const int s0 = offsets[n];
    const int s1 = offsets[n + 1];

    float acc[24];
    #pragma unroll
    for (int i = 0; i < 24; ++i) acc[i] = 0.f;
    float z0 = 0.f, z1 = 0.f;

#define ACCUM(U0, U1, U2, SC) \
    acc[0]  += SC.x * bf2f_lo(U0.x); acc[1]  += SC.x * bf2f_hi(U0.x); \
    acc[2]  += SC.x * bf2f_lo(U0.y); acc[3]  += SC.x * bf2f_hi(U0.y); \
    acc[4]  += SC.x * bf2f_lo(U0.z); acc[5]  += SC.x * bf2f_hi(U0.z); \
    acc[6]  += SC.x * bf2f_lo(U0.w); acc[7]  += SC.x * bf2f_hi(U0.w); \
    acc[8]  += SC.x * bf2f_lo(U1.x); acc[9]  += SC.x * bf2f_hi(U1.x); \
    acc[10] += SC.x * bf2f_lo(U1.y); acc[11] += SC.x * bf2f_hi(U1.y); \
    acc[12] += SC.y * bf2f_lo(U1.z); acc[13] += SC.y * bf2f_hi(U1.z); \
    acc[14] += SC.y * bf2f_lo(U1.w); acc[15] += SC.y * bf2f_hi(U1.w); \
    acc[16] += SC.y * bf2f_lo(U2.x); acc[17] += SC.y * bf2f_hi(U2.x); \
    acc[18] += SC.y * bf2f_lo(U2.y); acc[19] += SC.y * bf2f_hi(U2.y); \
    acc[20] += SC.y * bf2f_lo(U2.z); acc[21] += SC.y * bf2f_hi(U2.z); \
    acc[22] += SC.y * bf2f_lo(U2.w); acc[23] += SC.y * bf2f_hi(U2.w);

    int p = s0;
    for (; p + 2 <= s1; p += 2) {
        const int srcA = sorted_src[p];
        const int srcB = sorted_src[p + 1];
        const float2 scA = *(const float2*)&score_s[(size_t)p * 8 + g * 2];
        const float2 scB = *(const float2*)&score_s[(size_t)(p + 1) * 8 + g * 2];
        const uint4* VA = (const uint4*)&Vb[(size_t)srcA * 96 + g * 24];
        const uint4* VB = (const uint4*)&Vb[(size_t)srcB * 96 + g * 24];
        const uint4 a0 = VA[0], a1 = VA[1], a2 = VA[2];
        const uint4 b0 = VB[0], b1 = VB[1], b2 = VB[2];
        ACCUM(a0, a1, a2, scA);
        ACCUM(b0, b1, b2, scB);
        z0 += scA.x + scB.x;
        z1 += scA.y + scB.y;
    }
    if (p < s1) {
        const int srcA = sorted_src[p];
        const float2 scA = *(const float2*)&score_s[(size_t)p * 8 + g * 2];
        const uint4* VA = (const uint4*)&Vb[(size_t)srcA * 96 + g * 24];
        const uint4 a0 = VA[0], a1 = VA[1], a2 = VA[2];
        ACCUM(a0, a1, a2, scA);
        z0 += scA.x;
        z1 += scA.y;
    }
#undef ACCUM

    const float i0 = 1.f / (z0 + 1e-6f);
    const float i1 = 1.f / (z1 + 1e-6f);
    float o[24];
    #pragma unroll
    for (int k = 0; k < 24; ++k) o[k] = acc[k] * (k < 12 ? i0 : i1);
    float* dst = &out[(size_t)n * 96 + g * 24];
    #pragma unroll
    for (int k = 0; k < 6; ++k)
        *(float4*)&dst[k * 4] = make_float4(o[k*4], o[k*4+1], o[k*4+2], o[k*4+3]);
}

// ---------------------------------------------------------------------------
extern "C" void kernel_launch(void* const* d_in, const int* in_sizes, int n_in,
                              void* d_out, int out_size, void* d_ws, size_t ws_size,
                              hipStream_t stream) {
    const float* x  = (const float*)d_in[0];
    const int*   ei = (const int*)d_in[1];   // [2, E] int32 (JAX x64 disabled)
    const float* ea = (const float*)d_in[2];
    const float* Wq = (const float*)d_in[3];
    const float* bq = (const float*)d_in[4];
    const float* Wk = (const float*)d_in[5];
    const float* bk = (const float*)d_in[6];
    const float* We = (const float*)d_in[7];
    const float* be = (const float*)d_in[8];
    const float* Wv = (const float*)d_in[9];
    const float* bv = (const float*)d_in[10];

    float* out = (float*)d_out;

    // workspace: Qb | Kb | Vb (bf16) | score_s | offsets | cursor | sorted_src | WeT
    const size_t nqkv = (size_t)N_NODES * 96;
    unsigned short* Qb = (unsigned short*)d_ws;
    unsigned short* Kb = Qb + nqkv;
    unsigned short* Vb = Kb + nqkv;
    float* score_s  = (float*)(Vb + nqkv);                   // [E,8]
    int* offsets    = (int*)(score_s + (size_t)N_EDGES * 8); // [N+1]
    int* cursor     = offsets + (N_NODES + 1);               // [N]
    int* sorted_src = cursor + N_NODES;                      // [E]
    unsigned short* WeT = (unsigned short*)(sorted_src + N_EDGES);  // [96*96]

    hipMemsetAsync(cursor, 0, N_NODES * sizeof(int), stream);

    wet_kernel<<<dim3(36), 256, 0, stream>>>(We, WeT);

    qkv_kernel<<<dim3((N_NODES + 63) / 64), 256, 0, stream>>>(
        x, Wq, bq, Wk, bk, Wv, bv, Qb, Kb, Vb);

    hist_kernel<<<dim3((N_EDGES + 255) / 256), 256, 0, stream>>>(ei, cursor);
    scan_kernel<<<dim3(1), 1024, 0, stream>>>(cursor, offsets);

    score_kernel<<<dim3(N_EDGES / 64), 256, 0, stream>>>(
        ea, ei, WeT, be, Qb, Kb, cursor, sorted_src, score_s);

    gather_kernel<<<dim3((N_NODES * 4 + 255) / 256), 256, 0, stream>>>(
        offsets, sorted_src, score_s, Vb, out);
}